// Round 10
// baseline (304.677 us; speedup 1.0000x reference)
//
#include <hip/hip_runtime.h>
#include <hip/hip_bf16.h>

#define SCALE 0.07216878364870322f   // (3*64)^-0.5
#define LOG2E 1.4426950408889634f
// Q is pre-scaled by SCALE*LOG2E so attention logits are in log2 units.

typedef __bf16 bf16x8 __attribute__((ext_vector_type(8)));
typedef float f32x16 __attribute__((ext_vector_type(16)));
typedef float f32x4v __attribute__((ext_vector_type(4)));
typedef unsigned int u32x4 __attribute__((ext_vector_type(4)));
typedef unsigned short u16;

#define MFMA(a, b, c) __builtin_amdgcn_mfma_f32_32x32x16_bf16(a, b, c, 0, 0, 0)
#define MFMA16(a, b, c) __builtin_amdgcn_mfma_f32_16x16x32_bf16(a, b, c, 0, 0, 0)

__device__ __forceinline__ u16 b16(float v) { return __builtin_bit_cast(u16, (__bf16)v); }
__device__ __forceinline__ float fb16(u16 u) {
    unsigned int t = (unsigned int)u << 16;
    return __builtin_bit_cast(float, t);
}
__device__ __forceinline__ unsigned int splitpack(float v) {
    u16 h = b16(v);
    float r = v - fb16(h);
    return (unsigned int)h | ((unsigned int)b16(r) << 16);
}
__device__ __forceinline__ unsigned int pack2(float a, float b) {
    return (unsigned int)b16(a) | ((unsigned int)b16(b) << 16);
}
__device__ __forceinline__ void gload16(const void* g, void* l) {
    __builtin_amdgcn_global_load_lds((const __attribute__((address_space(1))) void*)g,
                                     (__attribute__((address_space(3))) void*)l, 16, 0, 0);
}

// ---------------- K1: QKV projection, MFMA split-bf16, zero-LDS main loop ----
// Q (16x16 B-frag): Qhi/Qlo off = ((bh*128+i16)*6+kc)*512 + lane*8
// K/V fused tile-contiguous KVf: tile(bh,jt32) = 36KB: [Khi 6144u16 | Klo 6144 | V 6144]
__global__ __launch_bounds__(256) void qkv_mfma(const float* __restrict__ x,
                                                const float* __restrict__ wq,
                                                u16* __restrict__ Qhi, u16* __restrict__ Qlo,
                                                u16* __restrict__ KVf) {
    __shared__ unsigned int ldsr[2][32][196];
    const int tid = threadIdx.x;
    const int lane = tid & 63, w = tid >> 6, hf = lane >> 5, l31 = lane & 31;
    const int lq = lane & 15, gq = lane >> 4;   // 16x16-frag coords
    const int o0 = blockIdx.x * 64;
    const int n0 = blockIdx.y * 128;
    const int b = blockIdx.z;
    const int nw0 = n0 + w * 32;
    const int part = o0 >> 9;
    const int h = (o0 >> 6) & 7;
    const int bh = b * 8 + h;

    const float* xp = x + ((size_t)(b * 2048 + nw0 + l31)) * 768 + hf * 24;
    const float* wp0 = wq + (size_t)(o0 + l31) * 256 + hf * 8;
    const float* wp1 = wp0 + 32 * 256;

    f32x16 acc[3][2] = {};
    #pragma unroll 2
    for (int k0 = 0; k0 < 16; ++k0) {
        float xf[24], wf0[8], wf1[8];
        #pragma unroll
        for (int q = 0; q < 6; ++q) {
            f32x4v t = *(const f32x4v*)(xp + k0 * 48 + q * 4);
            xf[q * 4 + 0] = t[0]; xf[q * 4 + 1] = t[1];
            xf[q * 4 + 2] = t[2]; xf[q * 4 + 3] = t[3];
        }
        {
            f32x4v t0 = *(const f32x4v*)(wp0 + k0 * 16);
            f32x4v t1 = *(const f32x4v*)(wp0 + k0 * 16 + 4);
            f32x4v t2 = *(const f32x4v*)(wp1 + k0 * 16);
            f32x4v t3 = *(const f32x4v*)(wp1 + k0 * 16 + 4);
            #pragma unroll
            for (int e = 0; e < 4; ++e) {
                wf0[e] = t0[e]; wf0[4 + e] = t1[e];
                wf1[e] = t2[e]; wf1[4 + e] = t3[e];
            }
        }
        bf16x8 xh[3], xl[3], wh[2], wl[2];
        #pragma unroll
        for (int c = 0; c < 3; ++c)
            #pragma unroll
            for (int e = 0; e < 8; ++e) {
                float v = xf[e * 3 + c];
                __bf16 hi = (__bf16)v;
                xh[c][e] = hi;
                xl[c][e] = (__bf16)(v - (float)hi);
            }
        #pragma unroll
        for (int e = 0; e < 8; ++e) {
            { float v = wf0[e]; __bf16 hi = (__bf16)v; wh[0][e] = hi; wl[0][e] = (__bf16)(v - (float)hi); }
            { float v = wf1[e]; __bf16 hi = (__bf16)v; wh[1][e] = hi; wl[1][e] = (__bf16)(v - (float)hi); }
        }
        #pragma unroll
        for (int c = 0; c < 3; ++c)
            #pragma unroll
            for (int ot = 0; ot < 2; ++ot) {
                acc[c][ot] = MFMA(xh[c], wh[ot], acc[c][ot]);
                acc[c][ot] = MFMA(xl[c], wh[ot], acc[c][ot]);
                acc[c][ot] = MFMA(xh[c], wl[ot], acc[c][ot]);
            }
    }

    #pragma unroll
    for (int round = 0; round < 2; ++round) {
        __syncthreads();
        if ((w >> 1) == round) {
            unsigned int (*L)[196] = ldsr[w & 1];
            #pragma unroll
            for (int c = 0; c < 3; ++c)
                #pragma unroll
                for (int ot = 0; ot < 2; ++ot)
                    #pragma unroll
                    for (int r = 0; r < 16; ++r) {
                        float v = acc[c][ot][r];
                        if (part == 0) v *= (SCALE * LOG2E);
                        int nn = (r & 3) + 8 * (r >> 2) + 4 * hf;
                        int dcol = 3 * (ot * 32 + l31) + c;
                        L[nn][dcol] = (part == 2) ? (unsigned int)b16(v) : splitpack(v);
                    }
            if (part < 2) {
                #pragma unroll
                for (int is = 0; is < 2; ++is)
                    #pragma unroll
                    for (int kc = 0; kc < 6; ++kc) {
                        const unsigned int* p = &L[is * 16 + lq][kc * 32 + gq * 8];
                        u32x4 a = *(const u32x4*)p;
                        u32x4 bq = *(const u32x4*)(p + 4);
                        u32x4 hi = { (a[0] & 0xffffu) | (a[1] << 16), (a[2] & 0xffffu) | (a[3] << 16),
                                     (bq[0] & 0xffffu) | (bq[1] << 16), (bq[2] & 0xffffu) | (bq[3] << 16) };
                        u32x4 lo = { (a[0] >> 16) | (a[1] & 0xffff0000u), (a[2] >> 16) | (a[3] & 0xffff0000u),
                                     (bq[0] >> 16) | (bq[1] & 0xffff0000u), (bq[2] >> 16) | (bq[3] & 0xffff0000u) };
                        if (part == 0) {
                            size_t off = ((size_t)(bh * 128 + (nw0 >> 4) + is) * 6 + kc) * 512 + lane * 8;
                            *(u32x4*)(Qhi + off) = hi;
                            *(u32x4*)(Qlo + off) = lo;
                        } else {
                            size_t off = (size_t)(bh * 64 + (nw0 >> 5)) * 18432 + (is * 6 + kc) * 512 + lane * 8;
                            *(u32x4*)(KVf + off) = hi;
                            *(u32x4*)(KVf + off + 6144) = lo;
                        }
                    }
            } else {
                u16* vp = KVf + (size_t)(bh * 64 + (nw0 >> 5)) * 18432 + 12288 + lane * 8;
                #pragma unroll
                for (int d = 0; d < 12; ++d) {
                    unsigned int t[8];
                    #pragma unroll
                    for (int e = 0; e < 8; ++e)
                        t[e] = L[gq * 8 + e][d * 16 + lq];
                    u32x4 pk = { (t[0] & 0xffffu) | (t[1] << 16), (t[2] & 0xffffu) | (t[3] << 16),
                                 (t[4] & 0xffffu) | (t[5] << 16), (t[6] & 0xffffu) | (t[7] << 16) };
                    *(u32x4*)(vp + d * 512) = pk;
                }
            }
        }
    }
}

// ---------------- K2: MFMA flash attention, 16x16x32, 32 i-rows/wave ---------
// grid 512 (XCD-swizzled), block 256 (4 waves). Wave owns 32 i-rows (2 x 16-row sets);
// K/V frags read from LDS ONCE per tile, consumed by both i-sets (2x arithmetic intensity).
// 72KB dbuf LDS -> 2 blocks/CU; j-halved (half in grid), combined by attn_combine.
__global__ __launch_bounds__(256) void attn_mfma(
    const u16* __restrict__ Qhi, const u16* __restrict__ Qlo,
    const u16* __restrict__ KVf, u16* __restrict__ Opart, float* __restrict__ MLp) {
    __shared__ __align__(16) u16 lds[2][18432];  // per buf: Khi[6144]|Klo[6144]|V[6144]
    const int tid = threadIdx.x;
    const int lane = tid & 63;
    const int w = tid >> 6;          // 0..3
    const int g = lane >> 4;         // 0..3
    const int i = lane & 15;
    // XCD decode: id&7 = XCD; 16 blocks of one (bh,half) group share an XCD.
    const int id = blockIdx.x;                     // 0..511
    const int rem = id >> 3;                       // 0..63
    const int grp = ((rem >> 4) << 3) | (id & 7);  // 0..31: (bh,half)
    const int itile = rem & 15;                    // 0..15
    const int bh = grp >> 1;
    const int half = grp & 1;

    // Q B-frags resident (hi+lo) for both 16-row sets: 96 VGPRs
    bf16x8 qh[2][6], ql[2][6];
    #pragma unroll
    for (int is = 0; is < 2; ++is) {
        size_t qb = (size_t)(bh * 128 + itile * 8 + w * 2 + is) * 3072 + (size_t)lane * 8;
        #pragma unroll
        for (int kc = 0; kc < 6; ++kc) {
            qh[is][kc] = *(const bf16x8*)(Qhi + qb + kc * 512);
            ql[is][kc] = *(const bf16x8*)(Qlo + qb + kc * 512);
        }
    }

    const char* gKV = (const char*)KVf + (size_t)bh * 2359296;  // 64 tiles * 36864 B
    auto stage = [&](int buf, int jtAbs) {
        const char* src = gKV + (size_t)jtAbs * 36864;
        char* dst = (char*)&lds[buf][0];
        #pragma unroll
        for (int s = 0; s < 9; ++s) {
            const int c16 = (tid + s * 256) * 16;
            gload16(src + c16, dst + c16);
        }
    };

    const int jt0 = half * 32;
    stage(0, jt0);
    __syncthreads();
    int cur = 0;

    f32x4v o[2][12] = {};
    float m_run[2] = {-1e30f, -1e30f}, l_run[2] = {0.f, 0.f};

    for (int t = 0; t < 32; ++t) {
        if (t + 1 < 32) stage(cur ^ 1, jt0 + t + 1);
        const u16* L = &lds[cur][0];

        // ---- S^T = K · Q^T : K frags read once, 4 indep chains x 3 seq terms ----
        f32x4v s4[2][2] = {};   // [iset][js]
        __builtin_amdgcn_s_setprio(1);
        #pragma unroll
        for (int kc = 0; kc < 6; ++kc) {
            bf16x8 kh0 = *(const bf16x8*)&L[(unsigned)(kc * 512) + lane * 8];
            bf16x8 kh1 = *(const bf16x8*)&L[(unsigned)((6 + kc) * 512) + lane * 8];
            bf16x8 kl0 = *(const bf16x8*)&L[6144u + (unsigned)(kc * 512) + lane * 8];
            bf16x8 kl1 = *(const bf16x8*)&L[6144u + (unsigned)((6 + kc) * 512) + lane * 8];
            s4[0][0] = MFMA16(kh0, qh[0][kc], s4[0][0]);
            s4[0][1] = MFMA16(kh1, qh[0][kc], s4[0][1]);
            s4[1][0] = MFMA16(kh0, qh[1][kc], s4[1][0]);
            s4[1][1] = MFMA16(kh1, qh[1][kc], s4[1][1]);
            s4[0][0] = MFMA16(kh0, ql[0][kc], s4[0][0]);
            s4[0][1] = MFMA16(kh1, ql[0][kc], s4[0][1]);
            s4[1][0] = MFMA16(kh0, ql[1][kc], s4[1][0]);
            s4[1][1] = MFMA16(kh1, ql[1][kc], s4[1][1]);
            s4[0][0] = MFMA16(kl0, qh[0][kc], s4[0][0]);
            s4[0][1] = MFMA16(kl1, qh[0][kc], s4[0][1]);
            s4[1][0] = MFMA16(kl0, qh[1][kc], s4[1][0]);
            s4[1][1] = MFMA16(kl1, qh[1][kc], s4[1][1]);
        }
        __builtin_amdgcn_s_setprio(0);

        // ---- online softmax (log2 domain) per i-set + P B-frag build ----
        bf16x8 pb[2];
        #pragma unroll
        for (int is = 0; is < 2; ++is) {
            float pm = -1e30f;
            #pragma unroll
            for (int js = 0; js < 2; ++js)
                #pragma unroll
                for (int r = 0; r < 4; ++r) pm = fmaxf(pm, s4[is][js][r]);
            pm = fmaxf(pm, __shfl_xor(pm, 16, 64));
            pm = fmaxf(pm, __shfl_xor(pm, 32, 64));
            if (!__all(pm <= m_run[is] + 8.0f)) {   // T13 defer-rescale
                float mnew = fmaxf(m_run[is], pm);
                float sc = exp2f(m_run[is] - mnew);
                l_run[is] *= sc;
                #pragma unroll
                for (int d = 0; d < 12; ++d) o[is][d] = o[is][d] * sc;
                m_run[is] = mnew;
            }
            float rs = 0.f;
            unsigned int w0[2], w1[2];
            #pragma unroll
            for (int js = 0; js < 2; ++js) {
                float p0 = exp2f(s4[is][js][0] - m_run[is]), p1 = exp2f(s4[is][js][1] - m_run[is]);
                float p2 = exp2f(s4[is][js][2] - m_run[is]), p3 = exp2f(s4[is][js][3] - m_run[is]);
                rs += (p0 + p1) + (p2 + p3);
                w0[js] = pack2(p0, p1);
                w1[js] = pack2(p2, p3);
            }
            rs += __shfl_xor(rs, 16, 64);
            rs += __shfl_xor(rs, 32, 64);
            l_run[is] += rs;

            // P^T B-frag: F[t] holds k=j'=g*8+2t,2t+1, col=i
            u32x4 F;
            const int slA = ((g & 1) << 5) + i;
            const int slB = slA + 16;
            const bool ghi = (g >> 1) != 0;
            { unsigned a0 = __shfl((int)w0[0], slA, 64), a1 = __shfl((int)w0[1], slA, 64); F[0] = ghi ? a1 : a0; }
            { unsigned a0 = __shfl((int)w1[0], slA, 64), a1 = __shfl((int)w1[1], slA, 64); F[1] = ghi ? a1 : a0; }
            { unsigned a0 = __shfl((int)w0[0], slB, 64), a1 = __shfl((int)w0[1], slB, 64); F[2] = ghi ? a1 : a0; }
            { unsigned a0 = __shfl((int)w1[0], slB, 64), a1 = __shfl((int)w1[1], slB, 64); F[3] = ghi ? a1 : a0; }
            pb[is] = __builtin_bit_cast(bf16x8, F);
        }

        // ---- O^T += V^T · P^T : V frags read once, used by both i-sets ----
        __builtin_amdgcn_s_setprio(1);
        #pragma unroll
        for (int d = 0; d < 12; ++d) {
            bf16x8 vf = *(const bf16x8*)&L[12288u + (unsigned)(d * 512) + lane * 8];
            o[0][d] = MFMA16(vf, pb[0], o[0][d]);
            o[1][d] = MFMA16(vf, pb[1], o[1][d]);
        }
        __builtin_amdgcn_s_setprio(0);

        if (t + 1 < 32) {
            __syncthreads();   // drains vmcnt: next buffer staged; cur reads done
            cur ^= 1;
        }
    }

    // ---- epilogue: unnormalized bf16 partial O + (m,l) per i-set ----
    #pragma unroll
    for (int is = 0; is < 2; ++is) {
        const int tI = bh * 128 + itile * 8 + w * 2 + is;   // 0..2047
        u16* Op = Opart + (size_t)(half * 2048 + tI) * 3072 + lane;
        #pragma unroll
        for (int d = 0; d < 12; ++d)
            #pragma unroll
            for (int r = 0; r < 4; ++r)
                Op[(d * 4 + r) * 64] = b16(o[is][d][r]);
        float* mlp = MLp + (size_t)(half * 2048 + tI) * 128 + lane * 2;
        mlp[0] = m_run[is];
        mlp[1] = l_run[is];
    }
}

// ---------------- K2b: combine j-halves -> att2 (split-pack frag layout) -----
__global__ __launch_bounds__(256) void attn_combine(const u16* __restrict__ Opart,
                                                    const float* __restrict__ MLp,
                                                    unsigned int* __restrict__ att2) {
    const int tid = threadIdx.x, lane = tid & 63, w = tid >> 6;
    const int g = lane >> 4, i = lane & 15;
    const int tI = blockIdx.x * 4 + w;             // 0..2047
    const int bh = tI >> 7;
    const float* mla = MLp + (size_t)tI * 128 + lane * 2;
    const float* mlb = MLp + (size_t)(2048 + tI) * 128 + lane * 2;
    float ma = mla[0], la = mla[1];
    float mb = mlb[0], lb = mlb[1];
    float mm = fmaxf(ma, mb);
    float wa = exp2f(ma - mm), wb = exp2f(mb - mm);
    float inv = 1.0f / (la * wa + lb * wb);
    const u16* Oa = Opart + (size_t)tI * 3072 + lane;
    const u16* Ob = Opart + (size_t)(2048 + tI) * 3072 + lane;
    const int b2 = bh >> 3, hh = bh & 7;
    const int ig = (tI & 127) * 16 + i;
    const int itq = ig >> 5, i31 = ig & 31;
    #pragma unroll
    for (int d = 0; d < 12; ++d)
        #pragma unroll
        for (int r = 0; r < 4; ++r) {
            float va = fb16(Oa[(d * 4 + r) * 64]);
            float vb = fb16(Ob[(d * 4 + r) * 64]);
            float v = (va * wa + vb * wb) * inv;
            int dc = d * 16 + g * 4 + r;
            int dd = dc / 3, cc2 = dc - dd * 3;
            int hd = hh * 64 + dd;
            int ks = hd >> 4, e = hd & 7;
            int ln = i31 | (((hd >> 3) & 1) << 5);
            size_t off = (((size_t)(b2 * 3 + cc2) * 32 + ks) * 64 + itq) * 512 + (size_t)ln * 8 + e;
            att2[off] = splitpack(v);
        }
}

// ---------------- K3: output projection, MFMA split-bf16, no LDS ----------------
__global__ __launch_bounds__(256) void out_mfma(const unsigned int* __restrict__ att2,
                                                const float* __restrict__ wo,
                                                float* __restrict__ out) {
    const int tid = threadIdx.x, lane = tid & 63, w = tid >> 6, hf = lane >> 5, l31 = lane & 31;
    const int o0 = blockIdx.x * 32;
    const int n5 = blockIdx.y * 4 + w;
    const int b = blockIdx.z;
    const float* wp = wo + (size_t)(o0 + l31) * 512 + hf * 8;
    const unsigned int* ap = att2 + ((size_t)(b * 3) * 2048 + n5) * 512 + (size_t)lane * 8;
    f32x16 acc[3] = {};
    #pragma unroll 2
    for (int ks = 0; ks < 32; ++ks) {
        bf16x8 wh, wl;
        {
            f32x4v t0 = *(const f32x4v*)(wp + ks * 16);
            f32x4v t1 = *(const f32x4v*)(wp + ks * 16 + 4);
            #pragma unroll
            for (int e = 0; e < 4; ++e) {
                { float v = t0[e]; __bf16 hi = (__bf16)v; wh[e] = hi; wl[e] = (__bf16)(v - (float)hi); }
                { float v = t1[e]; __bf16 hi = (__bf16)v; wh[4 + e] = hi; wl[4 + e] = (__bf16)(v - (float)hi); }
            }
        }
        #pragma unroll
        for (int c = 0; c < 3; ++c) {
            const unsigned int* pc = ap + (size_t)c * 1048576 + ks * 32768;
            u32x4 a0 = *(const u32x4*)pc;
            u32x4 a1 = *(const u32x4*)(pc + 4);
            union { bf16x8 v; u32x4 u; } H, Lo;
            H.u  = { (a0[0] & 0xffffu) | (a0[1] << 16), (a0[2] & 0xffffu) | (a0[3] << 16),
                     (a1[0] & 0xffffu) | (a1[1] << 16), (a1[2] & 0xffffu) | (a1[3] << 16) };
            Lo.u = { (a0[0] >> 16) | (a0[1] & 0xffff0000u), (a0[2] >> 16) | (a0[3] & 0xffff0000u),
                     (a1[0] >> 16) | (a1[1] & 0xffff0000u), (a1[2] >> 16) | (a1[1 + 2] & 0xffff0000u) };
            acc[c] = MFMA(H.v, wh, acc[c]);
            acc[c] = MFMA(Lo.v, wh, acc[c]);
            acc[c] = MFMA(H.v, wl, acc[c]);
        }
    }
    #pragma unroll
    for (int r = 0; r < 16; ++r) {
        int n = (n5 << 5) + (r & 3) + 8 * (r >> 2) + 4 * hf;
        size_t off = ((size_t)(b * 2048 + n) * 256 + o0 + l31) * 3;
        out[off]     = acc[0][r];
        out[off + 1] = acc[1][r];
        out[off + 2] = acc[2][r];
    }
}

extern "C" void kernel_launch(void* const* d_in, const int* in_sizes, int n_in,
                              void* d_out, int out_size, void* d_ws, size_t ws_size,
                              hipStream_t stream) {
    const float* x     = (const float*)d_in[0];
    const float* w_qkv = (const float*)d_in[1];
    const float* w_out = (const float*)d_in[2];
    float* out = (float*)d_out;

    const size_t NB = (size_t)16 * 2048 * 192;       // 6.29M u16 per Q buffer
    u16* Qhi = (u16*)d_ws;
    u16* Qlo = Qhi + NB;
    u16* KVf = Qlo + NB;                             // 16*64*18432 u16 (37.7MB)
    u16* Opart = KVf + (size_t)16 * 64 * 18432;      // 4096*3072 u16 = 25.2MB
    float* MLp = (float*)(Opart + (size_t)4096 * 3072);  // 4096*128 f32 = 2.1MB
    unsigned int* att2 = (unsigned int*)Qhi;         // reuses Qhi+Qlo (dead after attn)

    qkv_mfma<<<dim3(24, 16, 2), 256, 0, stream>>>(x, w_qkv, Qhi, Qlo, KVf);
    attn_mfma<<<dim3(512), 256, 0, stream>>>(Qhi, Qlo, KVf, Opart, MLp);
    attn_combine<<<dim3(512), 256, 0, stream>>>(Opart, MLp, att2);
    out_mfma<<<dim3(8, 16, 2), 256, 0, stream>>>(att2, w_out, out);
}

// Round 11
// 239.019 us; speedup vs baseline: 1.2747x; 1.2747x over previous
//
#include <hip/hip_runtime.h>
#include <hip/hip_bf16.h>

#define SCALE 0.07216878364870322f   // (3*64)^-0.5
#define LOG2E 1.4426950408889634f
// Q is pre-scaled by SCALE*LOG2E so attention logits are in log2 units.

typedef __bf16 bf16x8 __attribute__((ext_vector_type(8)));
typedef float f32x16 __attribute__((ext_vector_type(16)));
typedef float f32x4v __attribute__((ext_vector_type(4)));
typedef unsigned int u32x4 __attribute__((ext_vector_type(4)));
typedef unsigned short u16;

#define MFMA(a, b, c) __builtin_amdgcn_mfma_f32_32x32x16_bf16(a, b, c, 0, 0, 0)
#define MFMA16(a, b, c) __builtin_amdgcn_mfma_f32_16x16x32_bf16(a, b, c, 0, 0, 0)

__device__ __forceinline__ u16 b16(float v) { return __builtin_bit_cast(u16, (__bf16)v); }
__device__ __forceinline__ float fb16(u16 u) {
    unsigned int t = (unsigned int)u << 16;
    return __builtin_bit_cast(float, t);
}
__device__ __forceinline__ unsigned int splitpack(float v) {
    u16 h = b16(v);
    float r = v - fb16(h);
    return (unsigned int)h | ((unsigned int)b16(r) << 16);
}
__device__ __forceinline__ unsigned int pack2(float a, float b) {
    return (unsigned int)b16(a) | ((unsigned int)b16(b) << 16);
}
__device__ __forceinline__ void gload16(const void* g, void* l) {
    __builtin_amdgcn_global_load_lds((const __attribute__((address_space(1))) void*)g,
                                     (__attribute__((address_space(3))) void*)l, 16, 0, 0);
}

// ---------------- K1: QKV projection, MFMA split-bf16, zero-LDS main loop ----
// Q (16x16 B-frag): Qhi/Qlo off = ((bh*128+i16)*6+kc)*512 + lane*8
// K/V fused tile-contiguous KVf: tile(bh,jt32) = 36KB: [Khi 6144u16 | Klo 6144 | V 6144]
__global__ __launch_bounds__(256) void qkv_mfma(const float* __restrict__ x,
                                                const float* __restrict__ wq,
                                                u16* __restrict__ Qhi, u16* __restrict__ Qlo,
                                                u16* __restrict__ KVf) {
    __shared__ unsigned int ldsr[2][32][196];
    const int tid = threadIdx.x;
    const int lane = tid & 63, w = tid >> 6, hf = lane >> 5, l31 = lane & 31;
    const int lq = lane & 15, gq = lane >> 4;   // 16x16-frag coords
    const int o0 = blockIdx.x * 64;
    const int n0 = blockIdx.y * 128;
    const int b = blockIdx.z;
    const int nw0 = n0 + w * 32;
    const int part = o0 >> 9;
    const int h = (o0 >> 6) & 7;
    const int bh = b * 8 + h;

    const float* xp = x + ((size_t)(b * 2048 + nw0 + l31)) * 768 + hf * 24;
    const float* wp0 = wq + (size_t)(o0 + l31) * 256 + hf * 8;
    const float* wp1 = wp0 + 32 * 256;

    f32x16 acc[3][2] = {};
    #pragma unroll 2
    for (int k0 = 0; k0 < 16; ++k0) {
        float xf[24], wf0[8], wf1[8];
        #pragma unroll
        for (int q = 0; q < 6; ++q) {
            f32x4v t = *(const f32x4v*)(xp + k0 * 48 + q * 4);
            xf[q * 4 + 0] = t[0]; xf[q * 4 + 1] = t[1];
            xf[q * 4 + 2] = t[2]; xf[q * 4 + 3] = t[3];
        }
        {
            f32x4v t0 = *(const f32x4v*)(wp0 + k0 * 16);
            f32x4v t1 = *(const f32x4v*)(wp0 + k0 * 16 + 4);
            f32x4v t2 = *(const f32x4v*)(wp1 + k0 * 16);
            f32x4v t3 = *(const f32x4v*)(wp1 + k0 * 16 + 4);
            #pragma unroll
            for (int e = 0; e < 4; ++e) {
                wf0[e] = t0[e]; wf0[4 + e] = t1[e];
                wf1[e] = t2[e]; wf1[4 + e] = t3[e];
            }
        }
        bf16x8 xh[3], xl[3], wh[2], wl[2];
        #pragma unroll
        for (int c = 0; c < 3; ++c)
            #pragma unroll
            for (int e = 0; e < 8; ++e) {
                float v = xf[e * 3 + c];
                __bf16 hi = (__bf16)v;
                xh[c][e] = hi;
                xl[c][e] = (__bf16)(v - (float)hi);
            }
        #pragma unroll
        for (int e = 0; e < 8; ++e) {
            { float v = wf0[e]; __bf16 hi = (__bf16)v; wh[0][e] = hi; wl[0][e] = (__bf16)(v - (float)hi); }
            { float v = wf1[e]; __bf16 hi = (__bf16)v; wh[1][e] = hi; wl[1][e] = (__bf16)(v - (float)hi); }
        }
        #pragma unroll
        for (int c = 0; c < 3; ++c)
            #pragma unroll
            for (int ot = 0; ot < 2; ++ot) {
                acc[c][ot] = MFMA(xh[c], wh[ot], acc[c][ot]);
                acc[c][ot] = MFMA(xl[c], wh[ot], acc[c][ot]);
                acc[c][ot] = MFMA(xh[c], wl[ot], acc[c][ot]);
            }
    }

    #pragma unroll
    for (int round = 0; round < 2; ++round) {
        __syncthreads();
        if ((w >> 1) == round) {
            unsigned int (*L)[196] = ldsr[w & 1];
            #pragma unroll
            for (int c = 0; c < 3; ++c)
                #pragma unroll
                for (int ot = 0; ot < 2; ++ot)
                    #pragma unroll
                    for (int r = 0; r < 16; ++r) {
                        float v = acc[c][ot][r];
                        if (part == 0) v *= (SCALE * LOG2E);
                        int nn = (r & 3) + 8 * (r >> 2) + 4 * hf;
                        int dcol = 3 * (ot * 32 + l31) + c;
                        L[nn][dcol] = (part == 2) ? (unsigned int)b16(v) : splitpack(v);
                    }
            if (part < 2) {
                #pragma unroll
                for (int is = 0; is < 2; ++is)
                    #pragma unroll
                    for (int kc = 0; kc < 6; ++kc) {
                        const unsigned int* p = &L[is * 16 + lq][kc * 32 + gq * 8];
                        u32x4 a = *(const u32x4*)p;
                        u32x4 bq = *(const u32x4*)(p + 4);
                        u32x4 hi = { (a[0] & 0xffffu) | (a[1] << 16), (a[2] & 0xffffu) | (a[3] << 16),
                                     (bq[0] & 0xffffu) | (bq[1] << 16), (bq[2] & 0xffffu) | (bq[3] << 16) };
                        u32x4 lo = { (a[0] >> 16) | (a[1] & 0xffff0000u), (a[2] >> 16) | (a[3] & 0xffff0000u),
                                     (bq[0] >> 16) | (bq[1] & 0xffff0000u), (bq[2] >> 16) | (bq[3] & 0xffff0000u) };
                        if (part == 0) {
                            size_t off = ((size_t)(bh * 128 + (nw0 >> 4) + is) * 6 + kc) * 512 + lane * 8;
                            *(u32x4*)(Qhi + off) = hi;
                            *(u32x4*)(Qlo + off) = lo;
                        } else {
                            size_t off = (size_t)(bh * 64 + (nw0 >> 5)) * 18432 + (is * 6 + kc) * 512 + lane * 8;
                            *(u32x4*)(KVf + off) = hi;
                            *(u32x4*)(KVf + off + 6144) = lo;
                        }
                    }
            } else {
                u16* vp = KVf + (size_t)(bh * 64 + (nw0 >> 5)) * 18432 + 12288 + lane * 8;
                #pragma unroll
                for (int d = 0; d < 12; ++d) {
                    unsigned int t[8];
                    #pragma unroll
                    for (int e = 0; e < 8; ++e)
                        t[e] = L[gq * 8 + e][d * 16 + lq];
                    u32x4 pk = { (t[0] & 0xffffu) | (t[1] << 16), (t[2] & 0xffffu) | (t[3] << 16),
                                 (t[4] & 0xffffu) | (t[5] << 16), (t[6] & 0xffffu) | (t[7] << 16) };
                    *(u32x4*)(vp + d * 512) = pk;
                }
            }
        }
    }
}

// ---------------- K2: MFMA flash attention, 16x16x32, 32 i-rows/wave ---------
// grid 512 (XCD-swizzled), block 256 (4 waves). Wave owns 32 i-rows (2 x 16-row sets);
// K/V frags read from LDS ONCE per tile, consumed by both i-sets (2x arithmetic intensity).
// launch_bounds(256,2): unified regs <= 256 -> 2 waves/SIMD; 72KB dbuf -> 2 blocks/CU.
__global__ __launch_bounds__(256, 2) void attn_mfma(
    const u16* __restrict__ Qhi, const u16* __restrict__ Qlo,
    const u16* __restrict__ KVf, u16* __restrict__ Opart, float* __restrict__ MLp) {
    __shared__ __align__(16) u16 lds[2][18432];  // per buf: Khi[6144]|Klo[6144]|V[6144]
    const int tid = threadIdx.x;
    const int lane = tid & 63;
    const int w = tid >> 6;          // 0..3
    const int g = lane >> 4;         // 0..3
    const int i = lane & 15;
    // XCD decode: id&7 = XCD; 16 blocks of one (bh,half) group share an XCD.
    const int id = blockIdx.x;                     // 0..511
    const int rem = id >> 3;                       // 0..63
    const int grp = ((rem >> 4) << 3) | (id & 7);  // 0..31: (bh,half)
    const int itile = rem & 15;                    // 0..15
    const int bh = grp >> 1;
    const int half = grp & 1;

    // Q B-frags resident (hi+lo) for both 16-row sets: 96 VGPRs
    bf16x8 qh[2][6], ql[2][6];
    #pragma unroll
    for (int is = 0; is < 2; ++is) {
        size_t qb = (size_t)(bh * 128 + itile * 8 + w * 2 + is) * 3072 + (size_t)lane * 8;
        #pragma unroll
        for (int kc = 0; kc < 6; ++kc) {
            qh[is][kc] = *(const bf16x8*)(Qhi + qb + kc * 512);
            ql[is][kc] = *(const bf16x8*)(Qlo + qb + kc * 512);
        }
    }

    const char* gKV = (const char*)KVf + (size_t)bh * 2359296;  // 64 tiles * 36864 B
    auto stage = [&](int buf, int jtAbs) {
        const char* src = gKV + (size_t)jtAbs * 36864;
        char* dst = (char*)&lds[buf][0];
        #pragma unroll
        for (int s = 0; s < 9; ++s) {
            const int c16 = (tid + s * 256) * 16;
            gload16(src + c16, dst + c16);
        }
    };

    const int jt0 = half * 32;
    stage(0, jt0);
    __syncthreads();
    int cur = 0;

    f32x4v o[2][12] = {};
    float m_run[2] = {-1e30f, -1e30f}, l_run[2] = {0.f, 0.f};

    for (int t = 0; t < 32; ++t) {
        if (t + 1 < 32) stage(cur ^ 1, jt0 + t + 1);
        const u16* L = &lds[cur][0];

        // ---- S^T = K · Q^T : K frags read once, 4 indep chains x 3 seq terms ----
        f32x4v s4[2][2] = {};   // [iset][js]
        __builtin_amdgcn_s_setprio(1);
        #pragma unroll
        for (int kc = 0; kc < 6; ++kc) {
            bf16x8 kh0 = *(const bf16x8*)&L[(unsigned)(kc * 512) + lane * 8];
            bf16x8 kh1 = *(const bf16x8*)&L[(unsigned)((6 + kc) * 512) + lane * 8];
            bf16x8 kl0 = *(const bf16x8*)&L[6144u + (unsigned)(kc * 512) + lane * 8];
            bf16x8 kl1 = *(const bf16x8*)&L[6144u + (unsigned)((6 + kc) * 512) + lane * 8];
            s4[0][0] = MFMA16(kh0, qh[0][kc], s4[0][0]);
            s4[0][1] = MFMA16(kh1, qh[0][kc], s4[0][1]);
            s4[1][0] = MFMA16(kh0, qh[1][kc], s4[1][0]);
            s4[1][1] = MFMA16(kh1, qh[1][kc], s4[1][1]);
            s4[0][0] = MFMA16(kh0, ql[0][kc], s4[0][0]);
            s4[0][1] = MFMA16(kh1, ql[0][kc], s4[0][1]);
            s4[1][0] = MFMA16(kh0, ql[1][kc], s4[1][0]);
            s4[1][1] = MFMA16(kh1, ql[1][kc], s4[1][1]);
            s4[0][0] = MFMA16(kl0, qh[0][kc], s4[0][0]);
            s4[0][1] = MFMA16(kl1, qh[0][kc], s4[0][1]);
            s4[1][0] = MFMA16(kl0, qh[1][kc], s4[1][0]);
            s4[1][1] = MFMA16(kl1, qh[1][kc], s4[1][1]);
        }
        __builtin_amdgcn_s_setprio(0);

        // ---- online softmax (log2 domain) per i-set + P B-frag build ----
        bf16x8 pb[2];
        #pragma unroll
        for (int is = 0; is < 2; ++is) {
            float pm = -1e30f;
            #pragma unroll
            for (int js = 0; js < 2; ++js)
                #pragma unroll
                for (int r = 0; r < 4; ++r) pm = fmaxf(pm, s4[is][js][r]);
            pm = fmaxf(pm, __shfl_xor(pm, 16, 64));
            pm = fmaxf(pm, __shfl_xor(pm, 32, 64));
            if (!__all(pm <= m_run[is] + 8.0f)) {   // T13 defer-rescale
                float mnew = fmaxf(m_run[is], pm);
                float sc = exp2f(m_run[is] - mnew);
                l_run[is] *= sc;
                #pragma unroll
                for (int d = 0; d < 12; ++d) o[is][d] = o[is][d] * sc;
                m_run[is] = mnew;
            }
            float rs = 0.f;
            unsigned int w0[2], w1[2];
            #pragma unroll
            for (int js = 0; js < 2; ++js) {
                float p0 = exp2f(s4[is][js][0] - m_run[is]), p1 = exp2f(s4[is][js][1] - m_run[is]);
                float p2 = exp2f(s4[is][js][2] - m_run[is]), p3 = exp2f(s4[is][js][3] - m_run[is]);
                rs += (p0 + p1) + (p2 + p3);
                w0[js] = pack2(p0, p1);
                w1[js] = pack2(p2, p3);
            }
            rs += __shfl_xor(rs, 16, 64);
            rs += __shfl_xor(rs, 32, 64);
            l_run[is] += rs;

            // P^T B-frag: F[t] holds k=j'=g*8+2t,2t+1, col=i
            u32x4 F;
            const int slA = ((g & 1) << 5) + i;
            const int slB = slA + 16;
            const bool ghi = (g >> 1) != 0;
            { unsigned a0 = __shfl((int)w0[0], slA, 64), a1 = __shfl((int)w0[1], slA, 64); F[0] = ghi ? a1 : a0; }
            { unsigned a0 = __shfl((int)w1[0], slA, 64), a1 = __shfl((int)w1[1], slA, 64); F[1] = ghi ? a1 : a0; }
            { unsigned a0 = __shfl((int)w0[0], slB, 64), a1 = __shfl((int)w0[1], slB, 64); F[2] = ghi ? a1 : a0; }
            { unsigned a0 = __shfl((int)w1[0], slB, 64), a1 = __shfl((int)w1[1], slB, 64); F[3] = ghi ? a1 : a0; }
            pb[is] = __builtin_bit_cast(bf16x8, F);
        }

        // ---- O^T += V^T · P^T : V frags read once, used by both i-sets ----
        __builtin_amdgcn_s_setprio(1);
        #pragma unroll
        for (int d = 0; d < 12; ++d) {
            bf16x8 vf = *(const bf16x8*)&L[12288u + (unsigned)(d * 512) + lane * 8];
            o[0][d] = MFMA16(vf, pb[0], o[0][d]);
            o[1][d] = MFMA16(vf, pb[1], o[1][d]);
        }
        __builtin_amdgcn_s_setprio(0);

        if (t + 1 < 32) {
            __syncthreads();   // drains vmcnt: next buffer staged; cur reads done
            cur ^= 1;
        }
    }

    // ---- epilogue: unnormalized bf16 partial O + (m,l) per i-set ----
    #pragma unroll
    for (int is = 0; is < 2; ++is) {
        const int tI = bh * 128 + itile * 8 + w * 2 + is;   // 0..2047
        u16* Op = Opart + (size_t)(half * 2048 + tI) * 3072 + lane;
        #pragma unroll
        for (int d = 0; d < 12; ++d)
            #pragma unroll
            for (int r = 0; r < 4; ++r)
                Op[(d * 4 + r) * 64] = b16(o[is][d][r]);
        float* mlp = MLp + (size_t)(half * 2048 + tI) * 128 + lane * 2;
        mlp[0] = m_run[is];
        mlp[1] = l_run[is];
    }
}

// ---------------- K2b: combine j-halves -> att2 (split-pack frag layout) -----
__global__ __launch_bounds__(256) void attn_combine(const u16* __restrict__ Opart,
                                                    const float* __restrict__ MLp,
                                                    unsigned int* __restrict__ att2) {
    const int tid = threadIdx.x, lane = tid & 63, w = tid >> 6;
    const int g = lane >> 4, i = lane & 15;
    const int tI = blockIdx.x * 4 + w;             // 0..2047
    const int bh = tI >> 7;
    const float* mla = MLp + (size_t)tI * 128 + lane * 2;
    const float* mlb = MLp + (size_t)(2048 + tI) * 128 + lane * 2;
    float ma = mla[0], la = mla[1];
    float mb = mlb[0], lb = mlb[1];
    float mm = fmaxf(ma, mb);
    float wa = exp2f(ma - mm), wb = exp2f(mb - mm);
    float inv = 1.0f / (la * wa + lb * wb);
    const u16* Oa = Opart + (size_t)tI * 3072 + lane;
    const u16* Ob = Opart + (size_t)(2048 + tI) * 3072 + lane;
    const int b2 = bh >> 3, hh = bh & 7;
    const int ig = (tI & 127) * 16 + i;
    const int itq = ig >> 5, i31 = ig & 31;
    #pragma unroll
    for (int d = 0; d < 12; ++d)
        #pragma unroll
        for (int r = 0; r < 4; ++r) {
            float va = fb16(Oa[(d * 4 + r) * 64]);
            float vb = fb16(Ob[(d * 4 + r) * 64]);
            float v = (va * wa + vb * wb) * inv;
            int dc = d * 16 + g * 4 + r;
            int dd = dc / 3, cc2 = dc - dd * 3;
            int hd = hh * 64 + dd;
            int ks = hd >> 4, e = hd & 7;
            int ln = i31 | (((hd >> 3) & 1) << 5);
            size_t off = (((size_t)(b2 * 3 + cc2) * 32 + ks) * 64 + itq) * 512 + (size_t)ln * 8 + e;
            att2[off] = splitpack(v);
        }
}

// ---------------- K3: output projection, MFMA split-bf16, no LDS ----------------
__global__ __launch_bounds__(256) void out_mfma(const unsigned int* __restrict__ att2,
                                                const float* __restrict__ wo,
                                                float* __restrict__ out) {
    const int tid = threadIdx.x, lane = tid & 63, w = tid >> 6, hf = lane >> 5, l31 = lane & 31;
    const int o0 = blockIdx.x * 32;
    const int n5 = blockIdx.y * 4 + w;
    const int b = blockIdx.z;
    const float* wp = wo + (size_t)(o0 + l31) * 512 + hf * 8;
    const unsigned int* ap = att2 + ((size_t)(b * 3) * 2048 + n5) * 512 + (size_t)lane * 8;
    f32x16 acc[3] = {};
    #pragma unroll 2
    for (int ks = 0; ks < 32; ++ks) {
        bf16x8 wh, wl;
        {
            f32x4v t0 = *(const f32x4v*)(wp + ks * 16);
            f32x4v t1 = *(const f32x4v*)(wp + ks * 16 + 4);
            #pragma unroll
            for (int e = 0; e < 4; ++e) {
                { float v = t0[e]; __bf16 hi = (__bf16)v; wh[e] = hi; wl[e] = (__bf16)(v - (float)hi); }
                { float v = t1[e]; __bf16 hi = (__bf16)v; wh[4 + e] = hi; wl[4 + e] = (__bf16)(v - (float)hi); }
            }
        }
        #pragma unroll
        for (int c = 0; c < 3; ++c) {
            const unsigned int* pc = ap + (size_t)c * 1048576 + ks * 32768;
            u32x4 a0 = *(const u32x4*)pc;
            u32x4 a1 = *(const u32x4*)(pc + 4);
            union { bf16x8 v; u32x4 u; } H, Lo;
            H.u  = { (a0[0] & 0xffffu) | (a0[1] << 16), (a0[2] & 0xffffu) | (a0[3] << 16),
                     (a1[0] & 0xffffu) | (a1[1] << 16), (a1[2] & 0xffffu) | (a1[3] << 16) };
            Lo.u = { (a0[0] >> 16) | (a0[1] & 0xffff0000u), (a0[2] >> 16) | (a0[3] & 0xffff0000u),
                     (a1[0] >> 16) | (a1[1] & 0xffff0000u), (a1[2] >> 16) | (a1[3] & 0xffff0000u) };
            acc[c] = MFMA(H.v, wh, acc[c]);
            acc[c] = MFMA(Lo.v, wh, acc[c]);
            acc[c] = MFMA(H.v, wl, acc[c]);
        }
    }
    #pragma unroll
    for (int r = 0; r < 16; ++r) {
        int n = (n5 << 5) + (r & 3) + 8 * (r >> 2) + 4 * hf;
        size_t off = ((size_t)(b * 2048 + n) * 256 + o0 + l31) * 3;
        out[off]     = acc[0][r];
        out[off + 1] = acc[1][r];
        out[off + 2] = acc[2][r];
    }
}

extern "C" void kernel_launch(void* const* d_in, const int* in_sizes, int n_in,
                              void* d_out, int out_size, void* d_ws, size_t ws_size,
                              hipStream_t stream) {
    const float* x     = (const float*)d_in[0];
    const float* w_qkv = (const float*)d_in[1];
    const float* w_out = (const float*)d_in[2];
    float* out = (float*)d_out;

    const size_t NB = (size_t)16 * 2048 * 192;       // 6.29M u16 per Q buffer
    u16* Qhi = (u16*)d_ws;
    u16* Qlo = Qhi + NB;
    u16* KVf = Qlo + NB;                             // 16*64*18432 u16 (37.7MB)
    u16* Opart = KVf + (size_t)16 * 64 * 18432;      // 4096*3072 u16 = 25.2MB
    float* MLp = (float*)(Opart + (size_t)4096 * 3072);  // 4096*128 f32 = 2.1MB
    unsigned int* att2 = (unsigned int*)Qhi;         // reuses Qhi+Qlo (dead after attn)

    qkv_mfma<<<dim3(24, 16, 2), 256, 0, stream>>>(x, w_qkv, Qhi, Qlo, KVf);
    attn_mfma<<<dim3(512), 256, 0, stream>>>(Qhi, Qlo, KVf, Opart, MLp);
    attn_combine<<<dim3(512), 256, 0, stream>>>(Opart, MLp, att2);
    out_mfma<<<dim3(8, 16, 2), 256, 0, stream>>>(att2, w_out, out);
}

// Round 12
// 234.367 us; speedup vs baseline: 1.3000x; 1.0199x over previous
//
#include <hip/hip_runtime.h>
#include <hip/hip_bf16.h>

#define SCALE 0.07216878364870322f   // (3*64)^-0.5
#define LOG2E 1.4426950408889634f
// Q is pre-scaled by SCALE*LOG2E so attention logits are in log2 units.

typedef __bf16 bf16x8 __attribute__((ext_vector_type(8)));
typedef float f32x16 __attribute__((ext_vector_type(16)));
typedef float f32x4v __attribute__((ext_vector_type(4)));
typedef unsigned int u32x4 __attribute__((ext_vector_type(4)));
typedef unsigned short u16;

#define MFMA(a, b, c) __builtin_amdgcn_mfma_f32_32x32x16_bf16(a, b, c, 0, 0, 0)
#define MFMA16(a, b, c) __builtin_amdgcn_mfma_f32_16x16x32_bf16(a, b, c, 0, 0, 0)

__device__ __forceinline__ u16 b16(float v) { return __builtin_bit_cast(u16, (__bf16)v); }
__device__ __forceinline__ float fb16(u16 u) {
    unsigned int t = (unsigned int)u << 16;
    return __builtin_bit_cast(float, t);
}
__device__ __forceinline__ unsigned int splitpack(float v) {
    u16 h = b16(v);
    float r = v - fb16(h);
    return (unsigned int)h | ((unsigned int)b16(r) << 16);
}
__device__ __forceinline__ unsigned int pack2(float a, float b) {
    return (unsigned int)b16(a) | ((unsigned int)b16(b) << 16);
}
__device__ __forceinline__ void gload16(const void* g, void* l) {
    __builtin_amdgcn_global_load_lds((const __attribute__((address_space(1))) void*)g,
                                     (__attribute__((address_space(3))) void*)l, 16, 0, 0);
}

// ---------------- K1: QKV projection, MFMA split-bf16, zero-LDS main loop ----
// Q (16x16 B-frag): Qhi/Qlo off = ((bh*128+i16)*6+kc)*512 + lane*8
// K/V fused tile-contiguous KVf: tile(bh,jt32) = 36KB: [Khi 6144u16 | Klo 6144 | V 6144]
__global__ __launch_bounds__(256) void qkv_mfma(const float* __restrict__ x,
                                                const float* __restrict__ wq,
                                                u16* __restrict__ Qhi, u16* __restrict__ Qlo,
                                                u16* __restrict__ KVf) {
    __shared__ unsigned int ldsr[2][32][196];
    const int tid = threadIdx.x;
    const int lane = tid & 63, w = tid >> 6, hf = lane >> 5, l31 = lane & 31;
    const int lq = lane & 15, gq = lane >> 4;   // 16x16-frag coords
    const int o0 = blockIdx.x * 64;
    const int n0 = blockIdx.y * 128;
    const int b = blockIdx.z;
    const int nw0 = n0 + w * 32;
    const int part = o0 >> 9;
    const int h = (o0 >> 6) & 7;
    const int bh = b * 8 + h;

    const float* xp = x + ((size_t)(b * 2048 + nw0 + l31)) * 768 + hf * 24;
    const float* wp0 = wq + (size_t)(o0 + l31) * 256 + hf * 8;
    const float* wp1 = wp0 + 32 * 256;

    f32x16 acc[3][2] = {};
    #pragma unroll 2
    for (int k0 = 0; k0 < 16; ++k0) {
        float xf[24], wf0[8], wf1[8];
        #pragma unroll
        for (int q = 0; q < 6; ++q) {
            f32x4v t = *(const f32x4v*)(xp + k0 * 48 + q * 4);
            xf[q * 4 + 0] = t[0]; xf[q * 4 + 1] = t[1];
            xf[q * 4 + 2] = t[2]; xf[q * 4 + 3] = t[3];
        }
        {
            f32x4v t0 = *(const f32x4v*)(wp0 + k0 * 16);
            f32x4v t1 = *(const f32x4v*)(wp0 + k0 * 16 + 4);
            f32x4v t2 = *(const f32x4v*)(wp1 + k0 * 16);
            f32x4v t3 = *(const f32x4v*)(wp1 + k0 * 16 + 4);
            #pragma unroll
            for (int e = 0; e < 4; ++e) {
                wf0[e] = t0[e]; wf0[4 + e] = t1[e];
                wf1[e] = t2[e]; wf1[4 + e] = t3[e];
            }
        }
        bf16x8 xh[3], xl[3], wh[2], wl[2];
        #pragma unroll
        for (int c = 0; c < 3; ++c)
            #pragma unroll
            for (int e = 0; e < 8; ++e) {
                float v = xf[e * 3 + c];
                __bf16 hi = (__bf16)v;
                xh[c][e] = hi;
                xl[c][e] = (__bf16)(v - (float)hi);
            }
        #pragma unroll
        for (int e = 0; e < 8; ++e) {
            { float v = wf0[e]; __bf16 hi = (__bf16)v; wh[0][e] = hi; wl[0][e] = (__bf16)(v - (float)hi); }
            { float v = wf1[e]; __bf16 hi = (__bf16)v; wh[1][e] = hi; wl[1][e] = (__bf16)(v - (float)hi); }
        }
        #pragma unroll
        for (int c = 0; c < 3; ++c)
            #pragma unroll
            for (int ot = 0; ot < 2; ++ot) {
                acc[c][ot] = MFMA(xh[c], wh[ot], acc[c][ot]);
                acc[c][ot] = MFMA(xl[c], wh[ot], acc[c][ot]);
                acc[c][ot] = MFMA(xh[c], wl[ot], acc[c][ot]);
            }
    }

    #pragma unroll
    for (int round = 0; round < 2; ++round) {
        __syncthreads();
        if ((w >> 1) == round) {
            unsigned int (*L)[196] = ldsr[w & 1];
            #pragma unroll
            for (int c = 0; c < 3; ++c)
                #pragma unroll
                for (int ot = 0; ot < 2; ++ot)
                    #pragma unroll
                    for (int r = 0; r < 16; ++r) {
                        float v = acc[c][ot][r];
                        if (part == 0) v *= (SCALE * LOG2E);
                        int nn = (r & 3) + 8 * (r >> 2) + 4 * hf;
                        int dcol = 3 * (ot * 32 + l31) + c;
                        L[nn][dcol] = (part == 2) ? (unsigned int)b16(v) : splitpack(v);
                    }
            if (part < 2) {
                #pragma unroll
                for (int is = 0; is < 2; ++is)
                    #pragma unroll
                    for (int kc = 0; kc < 6; ++kc) {
                        const unsigned int* p = &L[is * 16 + lq][kc * 32 + gq * 8];
                        u32x4 a = *(const u32x4*)p;
                        u32x4 bq = *(const u32x4*)(p + 4);
                        u32x4 hi = { (a[0] & 0xffffu) | (a[1] << 16), (a[2] & 0xffffu) | (a[3] << 16),
                                     (bq[0] & 0xffffu) | (bq[1] << 16), (bq[2] & 0xffffu) | (bq[3] << 16) };
                        u32x4 lo = { (a[0] >> 16) | (a[1] & 0xffff0000u), (a[2] >> 16) | (a[3] & 0xffff0000u),
                                     (bq[0] >> 16) | (bq[1] & 0xffff0000u), (bq[2] >> 16) | (bq[3] & 0xffff0000u) };
                        if (part == 0) {
                            size_t off = ((size_t)(bh * 128 + (nw0 >> 4) + is) * 6 + kc) * 512 + lane * 8;
                            *(u32x4*)(Qhi + off) = hi;
                            *(u32x4*)(Qlo + off) = lo;
                        } else {
                            size_t off = (size_t)(bh * 64 + (nw0 >> 5)) * 18432 + (is * 6 + kc) * 512 + lane * 8;
                            *(u32x4*)(KVf + off) = hi;
                            *(u32x4*)(KVf + off + 6144) = lo;
                        }
                    }
            } else {
                u16* vp = KVf + (size_t)(bh * 64 + (nw0 >> 5)) * 18432 + 12288 + lane * 8;
                #pragma unroll
                for (int d = 0; d < 12; ++d) {
                    unsigned int t[8];
                    #pragma unroll
                    for (int e = 0; e < 8; ++e)
                        t[e] = L[gq * 8 + e][d * 16 + lq];
                    u32x4 pk = { (t[0] & 0xffffu) | (t[1] << 16), (t[2] & 0xffffu) | (t[3] << 16),
                                 (t[4] & 0xffffu) | (t[5] << 16), (t[6] & 0xffffu) | (t[7] << 16) };
                    *(u32x4*)(vp + d * 512) = pk;
                }
            }
        }
    }
}

// ---------------- K2: MFMA flash attention, 16x16x32, 32 i-rows/wave ---------
// grid 256 (XCD-swizzled), block 512 (8 waves): waves 0-3 do j[0,1024), 4-7 do
// j[1024,2048) for the SAME 128 i-rows. In-block f32 merge through LDS -> att2.
// Per half: 72KB dbuf LDS (144KB total, 1 block/CU, 2 waves/SIMD).
__global__ __launch_bounds__(512, 2) void attn_mfma(
    const u16* __restrict__ Qhi, const u16* __restrict__ Qlo,
    const u16* __restrict__ KVf, unsigned int* __restrict__ att2) {
    __shared__ __align__(16) u16 lds[2][2][18432];  // [half][buf]: Khi|Klo|V
    const int tid = threadIdx.x;
    const int lane = tid & 63;
    const int w = tid >> 6;          // 0..7
    const int half = w >> 2;
    const int wl = w & 3;
    const int g = lane >> 4;         // 0..3
    const int i = lane & 15;
    // XCD swizzle: 16 blocks of a bh on one XCD (2 bh per XCD, slabs fit 4MB L2).
    const int id = blockIdx.x;                 // 0..255
    const int bh = (id & 7) * 2 + (id >> 7);
    const int itile = (id >> 3) & 15;

    // Q B-frags resident (hi+lo) for both 16-row sets: 96 VGPRs
    bf16x8 qh[2][6], ql[2][6];
    #pragma unroll
    for (int is = 0; is < 2; ++is) {
        size_t qb = (size_t)(bh * 128 + itile * 8 + wl * 2 + is) * 3072 + (size_t)lane * 8;
        #pragma unroll
        for (int kc = 0; kc < 6; ++kc) {
            qh[is][kc] = *(const bf16x8*)(Qhi + qb + kc * 512);
            ql[is][kc] = *(const bf16x8*)(Qlo + qb + kc * 512);
        }
    }

    const char* gKV = (const char*)KVf + (size_t)bh * 2359296;  // 64 tiles * 36864 B
    const int t256 = tid & 255;
    auto stage = [&](int buf, int jtAbs) {
        const char* src = gKV + (size_t)jtAbs * 36864;
        char* dst = (char*)&lds[half][buf][0];
        #pragma unroll
        for (int s = 0; s < 9; ++s) {
            const int c16 = (t256 + s * 256) * 16;
            gload16(src + c16, dst + c16);
        }
    };

    const int jt0 = half * 32;
    stage(0, jt0);
    __syncthreads();
    int cur = 0;

    f32x4v o[2][12] = {};
    float m_run[2] = {-1e30f, -1e30f}, l_run[2] = {0.f, 0.f};

    for (int t = 0; t < 32; ++t) {
        if (t + 1 < 32) stage(cur ^ 1, jt0 + t + 1);
        const u16* L = &lds[half][cur][0];

        // ---- S^T = K · Q^T : K frags read once, 4 indep chains x 3 seq terms ----
        f32x4v s4[2][2] = {};   // [iset][js]
        __builtin_amdgcn_s_setprio(1);
        #pragma unroll
        for (int kc = 0; kc < 6; ++kc) {
            bf16x8 kh0 = *(const bf16x8*)&L[(unsigned)(kc * 512) + lane * 8];
            bf16x8 kh1 = *(const bf16x8*)&L[(unsigned)((6 + kc) * 512) + lane * 8];
            bf16x8 kl0 = *(const bf16x8*)&L[6144u + (unsigned)(kc * 512) + lane * 8];
            bf16x8 kl1 = *(const bf16x8*)&L[6144u + (unsigned)((6 + kc) * 512) + lane * 8];
            s4[0][0] = MFMA16(kh0, qh[0][kc], s4[0][0]);
            s4[0][1] = MFMA16(kh1, qh[0][kc], s4[0][1]);
            s4[1][0] = MFMA16(kh0, qh[1][kc], s4[1][0]);
            s4[1][1] = MFMA16(kh1, qh[1][kc], s4[1][1]);
            s4[0][0] = MFMA16(kh0, ql[0][kc], s4[0][0]);
            s4[0][1] = MFMA16(kh1, ql[0][kc], s4[0][1]);
            s4[1][0] = MFMA16(kh0, ql[1][kc], s4[1][0]);
            s4[1][1] = MFMA16(kh1, ql[1][kc], s4[1][1]);
            s4[0][0] = MFMA16(kl0, qh[0][kc], s4[0][0]);
            s4[0][1] = MFMA16(kl1, qh[0][kc], s4[0][1]);
            s4[1][0] = MFMA16(kl0, qh[1][kc], s4[1][0]);
            s4[1][1] = MFMA16(kl1, qh[1][kc], s4[1][1]);
        }
        __builtin_amdgcn_s_setprio(0);

        // ---- online softmax (log2 domain) per i-set + P B-frag build ----
        bf16x8 pb[2];
        #pragma unroll
        for (int is = 0; is < 2; ++is) {
            float pm = -1e30f;
            #pragma unroll
            for (int js = 0; js < 2; ++js)
                #pragma unroll
                for (int r = 0; r < 4; ++r) pm = fmaxf(pm, s4[is][js][r]);
            pm = fmaxf(pm, __shfl_xor(pm, 16, 64));
            pm = fmaxf(pm, __shfl_xor(pm, 32, 64));
            if (!__all(pm <= m_run[is] + 8.0f)) {   // T13 defer-rescale
                float mnew = fmaxf(m_run[is], pm);
                float sc = exp2f(m_run[is] - mnew);
                l_run[is] *= sc;
                #pragma unroll
                for (int d = 0; d < 12; ++d) o[is][d] = o[is][d] * sc;
                m_run[is] = mnew;
            }
            float rs = 0.f;
            unsigned int w0[2], w1[2];
            #pragma unroll
            for (int js = 0; js < 2; ++js) {
                float p0 = exp2f(s4[is][js][0] - m_run[is]), p1 = exp2f(s4[is][js][1] - m_run[is]);
                float p2 = exp2f(s4[is][js][2] - m_run[is]), p3 = exp2f(s4[is][js][3] - m_run[is]);
                rs += (p0 + p1) + (p2 + p3);
                w0[js] = pack2(p0, p1);
                w1[js] = pack2(p2, p3);
            }
            rs += __shfl_xor(rs, 16, 64);
            rs += __shfl_xor(rs, 32, 64);
            l_run[is] += rs;

            // P^T B-frag: F[t] holds k=j'=g*8+2t,2t+1, col=i
            u32x4 F;
            const int slA = ((g & 1) << 5) + i;
            const int slB = slA + 16;
            const bool ghi = (g >> 1) != 0;
            { unsigned a0 = __shfl((int)w0[0], slA, 64), a1 = __shfl((int)w0[1], slA, 64); F[0] = ghi ? a1 : a0; }
            { unsigned a0 = __shfl((int)w1[0], slA, 64), a1 = __shfl((int)w1[1], slA, 64); F[1] = ghi ? a1 : a0; }
            { unsigned a0 = __shfl((int)w0[0], slB, 64), a1 = __shfl((int)w0[1], slB, 64); F[2] = ghi ? a1 : a0; }
            { unsigned a0 = __shfl((int)w1[0], slB, 64), a1 = __shfl((int)w1[1], slB, 64); F[3] = ghi ? a1 : a0; }
            pb[is] = __builtin_bit_cast(bf16x8, F);
        }

        // ---- O^T += V^T · P^T : V frags read once, used by both i-sets ----
        __builtin_amdgcn_s_setprio(1);
        #pragma unroll
        for (int d = 0; d < 12; ++d) {
            bf16x8 vf = *(const bf16x8*)&L[12288u + (unsigned)(d * 512) + lane * 8];
            o[0][d] = MFMA16(vf, pb[0], o[0][d]);
            o[1][d] = MFMA16(vf, pb[1], o[1][d]);
        }
        __builtin_amdgcn_s_setprio(0);

        if (t + 1 < 32) {
            __syncthreads();   // drains vmcnt: next buffer staged; cur reads done
            cur ^= 1;
        }
    }

    // ---- in-block merge: half 1 publishes (o, m, l) via LDS; half 0 combines ----
    float* LM = (float*)&lds[0][0][0];   // 96KB o + 1KB ml  (<144KB)
    __syncthreads();
    if (half == 1) {
        #pragma unroll
        for (int is = 0; is < 2; ++is) {
            #pragma unroll
            for (int d = 0; d < 12; ++d)
                *(f32x4v*)&LM[(((wl * 2 + is) * 12 + d) * 64 + lane) * 4] = o[is][d];
            LM[24576 + ((wl * 2 + is) * 64 + lane) * 2 + 0] = m_run[is];
            LM[24576 + ((wl * 2 + is) * 64 + lane) * 2 + 1] = l_run[is];
        }
    }
    __syncthreads();
    if (half == 0) {
        const int b2 = bh >> 3, hh = bh & 7;
        #pragma unroll
        for (int is = 0; is < 2; ++is) {
            float mb = LM[24576 + ((wl * 2 + is) * 64 + lane) * 2 + 0];
            float lb = LM[24576 + ((wl * 2 + is) * 64 + lane) * 2 + 1];
            float mm = fmaxf(m_run[is], mb);
            float wa = exp2f(m_run[is] - mm);
            float wb = exp2f(mb - mm);
            float inv = 1.0f / (l_run[is] * wa + lb * wb);
            const int ig = (itile * 8 + wl * 2 + is) * 16 + i;
            const int itq = ig >> 5, i31 = ig & 31;
            #pragma unroll
            for (int d = 0; d < 12; ++d) {
                f32x4v vb = *(const f32x4v*)&LM[(((wl * 2 + is) * 12 + d) * 64 + lane) * 4];
                #pragma unroll
                for (int r = 0; r < 4; ++r) {
                    float v = (o[is][d][r] * wa + vb[r] * wb) * inv;
                    int dc = d * 16 + g * 4 + r;
                    int dd = dc / 3, cc2 = dc - dd * 3;
                    int hd = hh * 64 + dd;
                    int ks = hd >> 4, e = hd & 7;
                    int ln = i31 | (((hd >> 3) & 1) << 5);
                    size_t off = (((size_t)(b2 * 3 + cc2) * 32 + ks) * 64 + itq) * 512 + (size_t)ln * 8 + e;
                    att2[off] = splitpack(v);
                }
            }
        }
    }
}

// ---------------- K3: output projection, MFMA split-bf16, no LDS ----------------
__global__ __launch_bounds__(256) void out_mfma(const unsigned int* __restrict__ att2,
                                                const float* __restrict__ wo,
                                                float* __restrict__ out) {
    const int tid = threadIdx.x, lane = tid & 63, w = tid >> 6, hf = lane >> 5, l31 = lane & 31;
    const int o0 = blockIdx.x * 32;
    const int n5 = blockIdx.y * 4 + w;
    const int b = blockIdx.z;
    const float* wp = wo + (size_t)(o0 + l31) * 512 + hf * 8;
    const unsigned int* ap = att2 + ((size_t)(b * 3) * 2048 + n5) * 512 + (size_t)lane * 8;
    f32x16 acc[3] = {};
    #pragma unroll 2
    for (int ks = 0; ks < 32; ++ks) {
        bf16x8 wh, wl;
        {
            f32x4v t0 = *(const f32x4v*)(wp + ks * 16);
            f32x4v t1 = *(const f32x4v*)(wp + ks * 16 + 4);
            #pragma unroll
            for (int e = 0; e < 4; ++e) {
                { float v = t0[e]; __bf16 hi = (__bf16)v; wh[e] = hi; wl[e] = (__bf16)(v - (float)hi); }
                { float v = t1[e]; __bf16 hi = (__bf16)v; wh[4 + e] = hi; wl[4 + e] = (__bf16)(v - (float)hi); }
            }
        }
        #pragma unroll
        for (int c = 0; c < 3; ++c) {
            const unsigned int* pc = ap + (size_t)c * 1048576 + ks * 32768;
            u32x4 a0 = *(const u32x4*)pc;
            u32x4 a1 = *(const u32x4*)(pc + 4);
            union { bf16x8 v; u32x4 u; } H, Lo;
            H.u  = { (a0[0] & 0xffffu) | (a0[1] << 16), (a0[2] & 0xffffu) | (a0[3] << 16),
                     (a1[0] & 0xffffu) | (a1[1] << 16), (a1[2] & 0xffffu) | (a1[3] << 16) };
            Lo.u = { (a0[0] >> 16) | (a0[1] & 0xffff0000u), (a0[2] >> 16) | (a0[3] & 0xffff0000u),
                     (a1[0] >> 16) | (a1[1] & 0xffff0000u), (a1[2] >> 16) | (a1[3] & 0xffff0000u) };
            acc[c] = MFMA(H.v, wh, acc[c]);
            acc[c] = MFMA(Lo.v, wh, acc[c]);
            acc[c] = MFMA(H.v, wl, acc[c]);
        }
    }
    #pragma unroll
    for (int r = 0; r < 16; ++r) {
        int n = (n5 << 5) + (r & 3) + 8 * (r >> 2) + 4 * hf;
        size_t off = ((size_t)(b * 2048 + n) * 256 + o0 + l31) * 3;
        out[off]     = acc[0][r];
        out[off + 1] = acc[1][r];
        out[off + 2] = acc[2][r];
    }
}

extern "C" void kernel_launch(void* const* d_in, const int* in_sizes, int n_in,
                              void* d_out, int out_size, void* d_ws, size_t ws_size,
                              hipStream_t stream) {
    const float* x     = (const float*)d_in[0];
    const float* w_qkv = (const float*)d_in[1];
    const float* w_out = (const float*)d_in[2];
    float* out = (float*)d_out;

    const size_t NB = (size_t)16 * 2048 * 192;       // 6.29M u16 per Q buffer
    const size_t KVN = (size_t)16 * 64 * 18432;      // 18.87M u16 (37.7MB)
    u16* Qhi = (u16*)d_ws;
    u16* Qlo = Qhi + NB;
    u16* KVf = Qlo + NB;
    unsigned int* att2 = (unsigned int*)(KVf + KVN); // 25.2MB (Q/KV stay live during attn)

    qkv_mfma<<<dim3(24, 16, 2), 256, 0, stream>>>(x, w_qkv, Qhi, Qlo, KVf);
    attn_mfma<<<dim3(256), 512, 0, stream>>>(Qhi, Qlo, KVf, att2);
    out_mfma<<<dim3(8, 16, 2), 256, 0, stream>>>(att2, w_out, out);
}

// Round 13
// 226.535 us; speedup vs baseline: 1.3449x; 1.0346x over previous
//
#include <hip/hip_runtime.h>
#include <hip/hip_bf16.h>

#define SCALE 0.07216878364870322f   // (3*64)^-0.5
#define LOG2E 1.4426950408889634f
// Q is pre-scaled by SCALE*LOG2E so attention logits are in log2 units.

typedef __bf16 bf16x8 __attribute__((ext_vector_type(8)));
typedef float f32x16 __attribute__((ext_vector_type(16)));
typedef float f32x4v __attribute__((ext_vector_type(4)));
typedef unsigned int u32x4 __attribute__((ext_vector_type(4)));
typedef unsigned short u16;

#define MFMA(a, b, c) __builtin_amdgcn_mfma_f32_32x32x16_bf16(a, b, c, 0, 0, 0)
#define MFMA16(a, b, c) __builtin_amdgcn_mfma_f32_16x16x32_bf16(a, b, c, 0, 0, 0)

__device__ __forceinline__ u16 b16(float v) { return __builtin_bit_cast(u16, (__bf16)v); }
__device__ __forceinline__ float fb16(u16 u) {
    unsigned int t = (unsigned int)u << 16;
    return __builtin_bit_cast(float, t);
}
__device__ __forceinline__ unsigned int splitpack(float v) {
    u16 h = b16(v);
    float r = v - fb16(h);
    return (unsigned int)h | ((unsigned int)b16(r) << 16);
}
__device__ __forceinline__ unsigned int pack2(float a, float b) {
    return (unsigned int)b16(a) | ((unsigned int)b16(b) << 16);
}
__device__ __forceinline__ void gload16(const void* g, void* l) {
    __builtin_amdgcn_global_load_lds((const __attribute__((address_space(1))) void*)g,
                                     (__attribute__((address_space(3))) void*)l, 16, 0, 0);
}

// ---------------- K1: QKV projection, MFMA split-bf16, zero-LDS main loop ----
// Flat grid 768, XCD-remapped: all 24 o-blocks sharing one (n,b) x-slice land
// on one XCD (x slice becomes L2-resident; x L3 traffic 300MB -> 12.6MB).
__global__ __launch_bounds__(256) void qkv_mfma(const float* __restrict__ x,
                                                const float* __restrict__ wq,
                                                u16* __restrict__ Qhi, u16* __restrict__ Qlo,
                                                u16* __restrict__ KVf) {
    __shared__ unsigned int ldsr[2][32][196];
    const int tid = threadIdx.x;
    const int lane = tid & 63, w = tid >> 6, hf = lane >> 5, l31 = lane & 31;
    const int lq = lane & 15, gq = lane >> 4;   // 16x16-frag coords
    // XCD decode: id&7 = XCD; jj/24 picks the (n,b) slice within the XCD.
    const int id = blockIdx.x;           // 0..767
    const int xcd = id & 7;
    const int jj = id >> 3;              // 0..95
    const int nb = xcd * 4 + jj / 24;    // 0..31
    const int ot = jj % 24;              // 0..23
    const int o0 = ot * 64;
    const int b = nb >> 4;
    const int n0 = (nb & 15) * 128;
    const int nw0 = n0 + w * 32;
    const int part = o0 >> 9;
    const int h = (o0 >> 6) & 7;
    const int bh = b * 8 + h;

    const float* xp = x + ((size_t)(b * 2048 + nw0 + l31)) * 768 + hf * 24;
    const float* wp0 = wq + (size_t)(o0 + l31) * 256 + hf * 8;
    const float* wp1 = wp0 + 32 * 256;

    f32x16 acc[3][2] = {};
    #pragma unroll 2
    for (int k0 = 0; k0 < 16; ++k0) {
        float xf[24], wf0[8], wf1[8];
        #pragma unroll
        for (int q = 0; q < 6; ++q) {
            f32x4v t = *(const f32x4v*)(xp + k0 * 48 + q * 4);
            xf[q * 4 + 0] = t[0]; xf[q * 4 + 1] = t[1];
            xf[q * 4 + 2] = t[2]; xf[q * 4 + 3] = t[3];
        }
        {
            f32x4v t0 = *(const f32x4v*)(wp0 + k0 * 16);
            f32x4v t1 = *(const f32x4v*)(wp0 + k0 * 16 + 4);
            f32x4v t2 = *(const f32x4v*)(wp1 + k0 * 16);
            f32x4v t3 = *(const f32x4v*)(wp1 + k0 * 16 + 4);
            #pragma unroll
            for (int e = 0; e < 4; ++e) {
                wf0[e] = t0[e]; wf0[4 + e] = t1[e];
                wf1[e] = t2[e]; wf1[4 + e] = t3[e];
            }
        }
        bf16x8 xh[3], xl[3], wh[2], wl[2];
        #pragma unroll
        for (int c = 0; c < 3; ++c)
            #pragma unroll
            for (int e = 0; e < 8; ++e) {
                float v = xf[e * 3 + c];
                __bf16 hi = (__bf16)v;
                xh[c][e] = hi;
                xl[c][e] = (__bf16)(v - (float)hi);
            }
        #pragma unroll
        for (int e = 0; e < 8; ++e) {
            { float v = wf0[e]; __bf16 hi = (__bf16)v; wh[0][e] = hi; wl[0][e] = (__bf16)(v - (float)hi); }
            { float v = wf1[e]; __bf16 hi = (__bf16)v; wh[1][e] = hi; wl[1][e] = (__bf16)(v - (float)hi); }
        }
        #pragma unroll
        for (int c = 0; c < 3; ++c)
            #pragma unroll
            for (int ot2 = 0; ot2 < 2; ++ot2) {
                acc[c][ot2] = MFMA(xh[c], wh[ot2], acc[c][ot2]);
                acc[c][ot2] = MFMA(xl[c], wh[ot2], acc[c][ot2]);
                acc[c][ot2] = MFMA(xh[c], wl[ot2], acc[c][ot2]);
            }
    }

    #pragma unroll
    for (int round = 0; round < 2; ++round) {
        __syncthreads();
        if ((w >> 1) == round) {
            unsigned int (*L)[196] = ldsr[w & 1];
            #pragma unroll
            for (int c = 0; c < 3; ++c)
                #pragma unroll
                for (int ot2 = 0; ot2 < 2; ++ot2)
                    #pragma unroll
                    for (int r = 0; r < 16; ++r) {
                        float v = acc[c][ot2][r];
                        if (part == 0) v *= (SCALE * LOG2E);
                        int nn = (r & 3) + 8 * (r >> 2) + 4 * hf;
                        int dcol = 3 * (ot2 * 32 + l31) + c;
                        L[nn][dcol] = (part == 2) ? (unsigned int)b16(v) : splitpack(v);
                    }
            if (part < 2) {
                #pragma unroll
                for (int is = 0; is < 2; ++is)
                    #pragma unroll
                    for (int kc = 0; kc < 6; ++kc) {
                        const unsigned int* p = &L[is * 16 + lq][kc * 32 + gq * 8];
                        u32x4 a = *(const u32x4*)p;
                        u32x4 bq = *(const u32x4*)(p + 4);
                        u32x4 hi = { (a[0] & 0xffffu) | (a[1] << 16), (a[2] & 0xffffu) | (a[3] << 16),
                                     (bq[0] & 0xffffu) | (bq[1] << 16), (bq[2] & 0xffffu) | (bq[3] << 16) };
                        u32x4 lo = { (a[0] >> 16) | (a[1] & 0xffff0000u), (a[2] >> 16) | (a[3] & 0xffff0000u),
                                     (bq[0] >> 16) | (bq[1] & 0xffff0000u), (bq[2] >> 16) | (bq[3] & 0xffff0000u) };
                        if (part == 0) {
                            size_t off = ((size_t)(bh * 128 + (nw0 >> 4) + is) * 6 + kc) * 512 + lane * 8;
                            *(u32x4*)(Qhi + off) = hi;
                            *(u32x4*)(Qlo + off) = lo;
                        } else {
                            size_t off = (size_t)(bh * 64 + (nw0 >> 5)) * 18432 + (is * 6 + kc) * 512 + lane * 8;
                            *(u32x4*)(KVf + off) = hi;
                            *(u32x4*)(KVf + off + 6144) = lo;
                        }
                    }
            } else {
                u16* vp = KVf + (size_t)(bh * 64 + (nw0 >> 5)) * 18432 + 12288 + lane * 8;
                #pragma unroll
                for (int d = 0; d < 12; ++d) {
                    unsigned int t[8];
                    #pragma unroll
                    for (int e = 0; e < 8; ++e)
                        t[e] = L[gq * 8 + e][d * 16 + lq];
                    u32x4 pk = { (t[0] & 0xffffu) | (t[1] << 16), (t[2] & 0xffffu) | (t[3] << 16),
                                 (t[4] & 0xffffu) | (t[5] << 16), (t[6] & 0xffffu) | (t[7] << 16) };
                    *(u32x4*)(vp + d * 512) = pk;
                }
            }
        }
    }
}

// ---------------- K2: MFMA flash attention (R11 loop), 32 i-rows/wave --------
// grid 512 (XCD-swizzled), block 256 (4 waves), launch_bounds(256,2) -> 2 waves/SIMD,
// 72KB dbuf -> 2 blocks/CU. Epilogue: unnormalized bf16 half-planes in att2-scatter
// layout + per-row (m,l); merged on the fly by out_mfma (no combine kernel).
__global__ __launch_bounds__(256, 2) void attn_mfma(
    const u16* __restrict__ Qhi, const u16* __restrict__ Qlo,
    const u16* __restrict__ KVf, u16* __restrict__ OpA, u16* __restrict__ OpB,
    float2* __restrict__ MLp) {
    __shared__ __align__(16) u16 lds[2][18432];  // per buf: Khi[6144]|Klo[6144]|V[6144]
    const int tid = threadIdx.x;
    const int lane = tid & 63;
    const int wl = tid >> 6;         // 0..3
    const int g = lane >> 4;         // 0..3
    const int i = lane & 15;
    // XCD decode: id&7 = XCD; 16 blocks of one (bh,half) group share an XCD.
    const int id = blockIdx.x;                     // 0..511
    const int rem = id >> 3;                       // 0..63
    const int grp = ((rem >> 4) << 3) | (id & 7);  // 0..31: (bh,half)
    const int itile = rem & 15;                    // 0..15
    const int bh = grp >> 1;
    const int half = grp & 1;

    // Q B-frags resident (hi+lo) for both 16-row sets: 96 VGPRs
    bf16x8 qh[2][6], ql[2][6];
    #pragma unroll
    for (int is = 0; is < 2; ++is) {
        size_t qb = (size_t)(bh * 128 + itile * 8 + wl * 2 + is) * 3072 + (size_t)lane * 8;
        #pragma unroll
        for (int kc = 0; kc < 6; ++kc) {
            qh[is][kc] = *(const bf16x8*)(Qhi + qb + kc * 512);
            ql[is][kc] = *(const bf16x8*)(Qlo + qb + kc * 512);
        }
    }

    const char* gKV = (const char*)KVf + (size_t)bh * 2359296;  // 64 tiles * 36864 B
    auto stage = [&](int buf, int jtAbs) {
        const char* src = gKV + (size_t)jtAbs * 36864;
        char* dst = (char*)&lds[buf][0];
        #pragma unroll
        for (int s = 0; s < 9; ++s) {
            const int c16 = (tid + s * 256) * 16;
            gload16(src + c16, dst + c16);
        }
    };

    const int jt0 = half * 32;
    stage(0, jt0);
    __syncthreads();
    int cur = 0;

    f32x4v o[2][12] = {};
    float m_run[2] = {-1e30f, -1e30f}, l_run[2] = {0.f, 0.f};

    for (int t = 0; t < 32; ++t) {
        if (t + 1 < 32) stage(cur ^ 1, jt0 + t + 1);
        const u16* L = &lds[cur][0];

        // ---- S^T = K · Q^T : K frags read once, 4 indep chains x 3 seq terms ----
        f32x4v s4[2][2] = {};   // [iset][js]
        __builtin_amdgcn_s_setprio(1);
        #pragma unroll
        for (int kc = 0; kc < 6; ++kc) {
            bf16x8 kh0 = *(const bf16x8*)&L[(unsigned)(kc * 512) + lane * 8];
            bf16x8 kh1 = *(const bf16x8*)&L[(unsigned)((6 + kc) * 512) + lane * 8];
            bf16x8 kl0 = *(const bf16x8*)&L[6144u + (unsigned)(kc * 512) + lane * 8];
            bf16x8 kl1 = *(const bf16x8*)&L[6144u + (unsigned)((6 + kc) * 512) + lane * 8];
            s4[0][0] = MFMA16(kh0, qh[0][kc], s4[0][0]);
            s4[0][1] = MFMA16(kh1, qh[0][kc], s4[0][1]);
            s4[1][0] = MFMA16(kh0, qh[1][kc], s4[1][0]);
            s4[1][1] = MFMA16(kh1, qh[1][kc], s4[1][1]);
            s4[0][0] = MFMA16(kh0, ql[0][kc], s4[0][0]);
            s4[0][1] = MFMA16(kh1, ql[0][kc], s4[0][1]);
            s4[1][0] = MFMA16(kh0, ql[1][kc], s4[1][0]);
            s4[1][1] = MFMA16(kh1, ql[1][kc], s4[1][1]);
            s4[0][0] = MFMA16(kl0, qh[0][kc], s4[0][0]);
            s4[0][1] = MFMA16(kl1, qh[0][kc], s4[0][1]);
            s4[1][0] = MFMA16(kl0, qh[1][kc], s4[1][0]);
            s4[1][1] = MFMA16(kl1, qh[1][kc], s4[1][1]);
        }
        __builtin_amdgcn_s_setprio(0);

        // ---- online softmax (log2 domain) per i-set + P B-frag build ----
        bf16x8 pb[2];
        #pragma unroll
        for (int is = 0; is < 2; ++is) {
            float pm = -1e30f;
            #pragma unroll
            for (int js = 0; js < 2; ++js)
                #pragma unroll
                for (int r = 0; r < 4; ++r) pm = fmaxf(pm, s4[is][js][r]);
            pm = fmaxf(pm, __shfl_xor(pm, 16, 64));
            pm = fmaxf(pm, __shfl_xor(pm, 32, 64));
            if (!__all(pm <= m_run[is] + 8.0f)) {   // T13 defer-rescale
                float mnew = fmaxf(m_run[is], pm);
                float sc = exp2f(m_run[is] - mnew);
                l_run[is] *= sc;
                #pragma unroll
                for (int d = 0; d < 12; ++d) o[is][d] = o[is][d] * sc;
                m_run[is] = mnew;
            }
            float rs = 0.f;
            unsigned int w0[2], w1[2];
            #pragma unroll
            for (int js = 0; js < 2; ++js) {
                float p0 = exp2f(s4[is][js][0] - m_run[is]), p1 = exp2f(s4[is][js][1] - m_run[is]);
                float p2 = exp2f(s4[is][js][2] - m_run[is]), p3 = exp2f(s4[is][js][3] - m_run[is]);
                rs += (p0 + p1) + (p2 + p3);
                w0[js] = pack2(p0, p1);
                w1[js] = pack2(p2, p3);
            }
            rs += __shfl_xor(rs, 16, 64);
            rs += __shfl_xor(rs, 32, 64);
            l_run[is] += rs;

            // P^T B-frag: F[t] holds k=j'=g*8+2t,2t+1, col=i
            u32x4 F;
            const int slA = ((g & 1) << 5) + i;
            const int slB = slA + 16;
            const bool ghi = (g >> 1) != 0;
            { unsigned a0 = __shfl((int)w0[0], slA, 64), a1 = __shfl((int)w0[1], slA, 64); F[0] = ghi ? a1 : a0; }
            { unsigned a0 = __shfl((int)w1[0], slA, 64), a1 = __shfl((int)w1[1], slA, 64); F[1] = ghi ? a1 : a0; }
            { unsigned a0 = __shfl((int)w0[0], slB, 64), a1 = __shfl((int)w0[1], slB, 64); F[2] = ghi ? a1 : a0; }
            { unsigned a0 = __shfl((int)w1[0], slB, 64), a1 = __shfl((int)w1[1], slB, 64); F[3] = ghi ? a1 : a0; }
            pb[is] = __builtin_bit_cast(bf16x8, F);
        }

        // ---- O^T += V^T · P^T : V frags read once, used by both i-sets ----
        __builtin_amdgcn_s_setprio(1);
        #pragma unroll
        for (int d = 0; d < 12; ++d) {
            bf16x8 vf = *(const bf16x8*)&L[12288u + (unsigned)(d * 512) + lane * 8];
            o[0][d] = MFMA16(vf, pb[0], o[0][d]);
            o[1][d] = MFMA16(vf, pb[1], o[1][d]);
        }
        __builtin_amdgcn_s_setprio(0);

        if (t + 1 < 32) {
            __syncthreads();   // drains vmcnt: next buffer staged; cur reads done
            cur ^= 1;
        }
    }

    // ---- epilogue: unnormalized bf16 half-plane in att2-scatter layout + (m,l) ----
    const int b2 = bh >> 3, hh = bh & 7;
    u16* P = half ? OpB : OpA;
    #pragma unroll
    for (int is = 0; is < 2; ++is) {
        const int ig = (itile * 8 + wl * 2 + is) * 16 + i;
        const int itq = ig >> 5, i31 = ig & 31;
        #pragma unroll
        for (int d = 0; d < 12; ++d)
            #pragma unroll
            for (int r = 0; r < 4; ++r) {
                int dc = d * 16 + g * 4 + r;
                int dd = dc / 3, cc2 = dc - dd * 3;
                int hd = hh * 64 + dd;
                int ks = hd >> 4, e = hd & 7;
                int ln = i31 | (((hd >> 3) & 1) << 5);
                size_t off = (((size_t)(b2 * 3 + cc2) * 32 + ks) * 64 + itq) * 512 + (size_t)ln * 8 + e;
                P[off] = b16(o[is][d][r]);
            }
        if (g == 0) {
            float2 ml; ml.x = m_run[is]; ml.y = l_run[is];
            MLp[(size_t)half * 32768 + bh * 2048 + ig] = ml;
        }
    }
}

// ---------------- K3: output projection + inline flash merge -----------------
// Reads both unnormalized half-planes, merges with per-(b,hh,n) weights, splits
// hi/lo in-flight, 3-term MFMA. No att2 intermediate, no combine kernel.
__global__ __launch_bounds__(256) void out_mfma(const u16* __restrict__ OpA,
                                                const u16* __restrict__ OpB,
                                                const float2* __restrict__ MLp,
                                                const float* __restrict__ wo,
                                                float* __restrict__ out) {
    const int tid = threadIdx.x, lane = tid & 63, w = tid >> 6, hf = lane >> 5, l31 = lane & 31;
    const int o0 = blockIdx.x * 32;
    const int n5 = blockIdx.y * 4 + w;
    const int b = blockIdx.z;
    const float* wp = wo + (size_t)(o0 + l31) * 512 + hf * 8;

    // per-hh merge weights for this lane's row n = n5*32 + l31
    float wa[8], wb[8], inv[8];
    #pragma unroll
    for (int hh = 0; hh < 8; ++hh) {
        size_t mi = (size_t)(b * 8 + hh) * 2048 + n5 * 32 + l31;
        float2 A = MLp[mi];
        float2 Bm = MLp[32768 + mi];
        float mm = fmaxf(A.x, Bm.x);
        wa[hh] = exp2f(A.x - mm);
        wb[hh] = exp2f(Bm.x - mm);
        inv[hh] = 1.0f / (A.y * wa[hh] + Bm.y * wb[hh]);
    }

    f32x16 acc[3] = {};
    #pragma unroll 2
    for (int ks = 0; ks < 32; ++ks) {
        const int hh = ks >> 2;
        const float waH = wa[hh], wbH = wb[hh], invH = inv[hh];
        bf16x8 wh, wl;
        {
            f32x4v t0 = *(const f32x4v*)(wp + ks * 16);
            f32x4v t1 = *(const f32x4v*)(wp + ks * 16 + 4);
            #pragma unroll
            for (int e = 0; e < 4; ++e) {
                { float v = t0[e]; __bf16 hi = (__bf16)v; wh[e] = hi; wl[e] = (__bf16)(v - (float)hi); }
                { float v = t1[e]; __bf16 hi = (__bf16)v; wh[4 + e] = hi; wl[4 + e] = (__bf16)(v - (float)hi); }
            }
        }
        #pragma unroll
        for (int c = 0; c < 3; ++c) {
            size_t pc = (size_t)(b * 3 + c) * 1048576 + (size_t)ks * 32768 + (size_t)n5 * 512 + (size_t)lane * 8;
            u32x4 aA = *(const u32x4*)(OpA + pc);
            u32x4 aB = *(const u32x4*)(OpB + pc);
            unsigned hiw[4], low[4];
            #pragma unroll
            for (int q = 0; q < 4; ++q) {
                unsigned ha = 0, la = 0;
                #pragma unroll
                for (int s = 0; s < 2; ++s) {
                    u16 ua = (u16)((aA[q] >> (s * 16)) & 0xffffu);
                    u16 ub = (u16)((aB[q] >> (s * 16)) & 0xffffu);
                    float v = (fb16(ua) * waH + fb16(ub) * wbH) * invH;
                    u16 hv = b16(v);
                    u16 lv = b16(v - fb16(hv));
                    ha |= ((unsigned)hv) << (s * 16);
                    la |= ((unsigned)lv) << (s * 16);
                }
                hiw[q] = ha; low[q] = la;
            }
            union { bf16x8 v; u32x4 u; } H, Lo;
            H.u  = { hiw[0], hiw[1], hiw[2], hiw[3] };
            Lo.u = { low[0], low[1], low[2], low[3] };
            acc[c] = MFMA(H.v, wh, acc[c]);
            acc[c] = MFMA(Lo.v, wh, acc[c]);
            acc[c] = MFMA(H.v, wl, acc[c]);
        }
    }
    #pragma unroll
    for (int r = 0; r < 16; ++r) {
        int n = (n5 << 5) + (r & 3) + 8 * (r >> 2) + 4 * hf;
        size_t off = ((size_t)(b * 2048 + n) * 256 + o0 + l31) * 3;
        out[off]     = acc[0][r];
        out[off + 1] = acc[1][r];
        out[off + 2] = acc[2][r];
    }
}

extern "C" void kernel_launch(void* const* d_in, const int* in_sizes, int n_in,
                              void* d_out, int out_size, void* d_ws, size_t ws_size,
                              hipStream_t stream) {
    const float* x     = (const float*)d_in[0];
    const float* w_qkv = (const float*)d_in[1];
    const float* w_out = (const float*)d_in[2];
    float* out = (float*)d_out;

    const size_t NB = (size_t)16 * 2048 * 192;       // 6.29M u16 per plane
    const size_t KVN = (size_t)16 * 64 * 18432;      // 18.87M u16 (37.7MB)
    u16* Qhi = (u16*)d_ws;
    u16* Qlo = Qhi + NB;
    u16* KVf = Qlo + NB;
    u16* OpA = KVf + KVN;                            // 12.6MB
    u16* OpB = OpA + NB;                             // 12.6MB
    float2* MLp = (float2*)(OpB + NB);               // 2*32768 float2 = 512KB

    qkv_mfma<<<dim3(768), 256, 0, stream>>>(x, w_qkv, Qhi, Qlo, KVf);
    attn_mfma<<<dim3(512), 256, 0, stream>>>(Qhi, Qlo, KVf, OpA, OpB, MLp);
    out_mfma<<<dim3(8, 16, 2), 256, 0, stream>>>(OpA, OpB, MLp, w_out, out);
}

// Round 14
// 218.119 us; speedup vs baseline: 1.3968x; 1.0386x over previous
//
#include <hip/hip_runtime.h>
#include <hip/hip_bf16.h>

#define SCALE 0.07216878364870322f   // (3*64)^-0.5
#define LOG2E 1.4426950408889634f
// Q is pre-scaled by SCALE*LOG2E so attention logits are in log2 units.

typedef __bf16 bf16x8 __attribute__((ext_vector_type(8)));
typedef float f32x16 __attribute__((ext_vector_type(16)));
typedef float f32x4v __attribute__((ext_vector_type(4)));
typedef unsigned int u32x4 __attribute__((ext_vector_type(4)));
typedef unsigned int u32x2 __attribute__((ext_vector_type(2)));
typedef unsigned short u16;

#define MFMA(a, b, c) __builtin_amdgcn_mfma_f32_32x32x16_bf16(a, b, c, 0, 0, 0)
#define MFMA16(a, b, c) __builtin_amdgcn_mfma_f32_16x16x32_bf16(a, b, c, 0, 0, 0)

__device__ __forceinline__ u16 b16(float v) { return __builtin_bit_cast(u16, (__bf16)v); }
__device__ __forceinline__ float fb16(u16 u) {
    unsigned int t = (unsigned int)u << 16;
    return __builtin_bit_cast(float, t);
}
__device__ __forceinline__ unsigned int splitpack(float v) {
    u16 h = b16(v);
    float r = v - fb16(h);
    return (unsigned int)h | ((unsigned int)b16(r) << 16);
}
__device__ __forceinline__ unsigned int pack2(float a, float b) {
    return (unsigned int)b16(a) | ((unsigned int)b16(b) << 16);
}
__device__ __forceinline__ void gload16(const void* g, void* l) {
    __builtin_amdgcn_global_load_lds((const __attribute__((address_space(1))) void*)g,
                                     (__attribute__((address_space(3))) void*)l, 16, 0, 0);
}

// ---------------- K1: QKV projection, MFMA split-bf16, zero-LDS main loop ----
// Flat grid 768, XCD-remapped: all 24 o-blocks sharing one (n,b) x-slice land
// on one XCD (x slice becomes L2-resident).
__global__ __launch_bounds__(256) void qkv_mfma(const float* __restrict__ x,
                                                const float* __restrict__ wq,
                                                u16* __restrict__ Qhi, u16* __restrict__ Qlo,
                                                u16* __restrict__ KVf) {
    __shared__ unsigned int ldsr[2][32][196];
    const int tid = threadIdx.x;
    const int lane = tid & 63, w = tid >> 6, hf = lane >> 5, l31 = lane & 31;
    const int lq = lane & 15, gq = lane >> 4;   // 16x16-frag coords
    const int id = blockIdx.x;           // 0..767
    const int xcd = id & 7;
    const int jj = id >> 3;              // 0..95
    const int nb = xcd * 4 + jj / 24;    // 0..31
    const int ot = jj % 24;              // 0..23
    const int o0 = ot * 64;
    const int b = nb >> 4;
    const int n0 = (nb & 15) * 128;
    const int nw0 = n0 + w * 32;
    const int part = o0 >> 9;
    const int h = (o0 >> 6) & 7;
    const int bh = b * 8 + h;

    const float* xp = x + ((size_t)(b * 2048 + nw0 + l31)) * 768 + hf * 24;
    const float* wp0 = wq + (size_t)(o0 + l31) * 256 + hf * 8;
    const float* wp1 = wp0 + 32 * 256;

    f32x16 acc[3][2] = {};
    #pragma unroll 2
    for (int k0 = 0; k0 < 16; ++k0) {
        float xf[24], wf0[8], wf1[8];
        #pragma unroll
        for (int q = 0; q < 6; ++q) {
            f32x4v t = *(const f32x4v*)(xp + k0 * 48 + q * 4);
            xf[q * 4 + 0] = t[0]; xf[q * 4 + 1] = t[1];
            xf[q * 4 + 2] = t[2]; xf[q * 4 + 3] = t[3];
        }
        {
            f32x4v t0 = *(const f32x4v*)(wp0 + k0 * 16);
            f32x4v t1 = *(const f32x4v*)(wp0 + k0 * 16 + 4);
            f32x4v t2 = *(const f32x4v*)(wp1 + k0 * 16);
            f32x4v t3 = *(const f32x4v*)(wp1 + k0 * 16 + 4);
            #pragma unroll
            for (int e = 0; e < 4; ++e) {
                wf0[e] = t0[e]; wf0[4 + e] = t1[e];
                wf1[e] = t2[e]; wf1[4 + e] = t3[e];
            }
        }
        bf16x8 xh[3], xl[3], wh[2], wl[2];
        #pragma unroll
        for (int c = 0; c < 3; ++c)
            #pragma unroll
            for (int e = 0; e < 8; ++e) {
                float v = xf[e * 3 + c];
                __bf16 hi = (__bf16)v;
                xh[c][e] = hi;
                xl[c][e] = (__bf16)(v - (float)hi);
            }
        #pragma unroll
        for (int e = 0; e < 8; ++e) {
            { float v = wf0[e]; __bf16 hi = (__bf16)v; wh[0][e] = hi; wl[0][e] = (__bf16)(v - (float)hi); }
            { float v = wf1[e]; __bf16 hi = (__bf16)v; wh[1][e] = hi; wl[1][e] = (__bf16)(v - (float)hi); }
        }
        #pragma unroll
        for (int c = 0; c < 3; ++c)
            #pragma unroll
            for (int ot2 = 0; ot2 < 2; ++ot2) {
                acc[c][ot2] = MFMA(xh[c], wh[ot2], acc[c][ot2]);
                acc[c][ot2] = MFMA(xl[c], wh[ot2], acc[c][ot2]);
                acc[c][ot2] = MFMA(xh[c], wl[ot2], acc[c][ot2]);
            }
    }

    #pragma unroll
    for (int round = 0; round < 2; ++round) {
        __syncthreads();
        if ((w >> 1) == round) {
            unsigned int (*L)[196] = ldsr[w & 1];
            #pragma unroll
            for (int c = 0; c < 3; ++c)
                #pragma unroll
                for (int ot2 = 0; ot2 < 2; ++ot2)
                    #pragma unroll
                    for (int r = 0; r < 16; ++r) {
                        float v = acc[c][ot2][r];
                        if (part == 0) v *= (SCALE * LOG2E);
                        int nn = (r & 3) + 8 * (r >> 2) + 4 * hf;
                        int dcol = 3 * (ot2 * 32 + l31) + c;
                        L[nn][dcol] = (part == 2) ? (unsigned int)b16(v) : splitpack(v);
                    }
            if (part < 2) {
                #pragma unroll
                for (int is = 0; is < 2; ++is)
                    #pragma unroll
                    for (int kc = 0; kc < 6; ++kc) {
                        const unsigned int* p = &L[is * 16 + lq][kc * 32 + gq * 8];
                        u32x4 a = *(const u32x4*)p;
                        u32x4 bq = *(const u32x4*)(p + 4);
                        u32x4 hi = { (a[0] & 0xffffu) | (a[1] << 16), (a[2] & 0xffffu) | (a[3] << 16),
                                     (bq[0] & 0xffffu) | (bq[1] << 16), (bq[2] & 0xffffu) | (bq[3] << 16) };
                        u32x4 lo = { (a[0] >> 16) | (a[1] & 0xffff0000u), (a[2] >> 16) | (a[3] & 0xffff0000u),
                                     (bq[0] >> 16) | (bq[1] & 0xffff0000u), (bq[2] >> 16) | (bq[3] & 0xffff0000u) };
                        if (part == 0) {
                            size_t off = ((size_t)(bh * 128 + (nw0 >> 4) + is) * 6 + kc) * 512 + lane * 8;
                            *(u32x4*)(Qhi + off) = hi;
                            *(u32x4*)(Qlo + off) = lo;
                        } else {
                            size_t off = (size_t)(bh * 64 + (nw0 >> 5)) * 18432 + (is * 6 + kc) * 512 + lane * 8;
                            *(u32x4*)(KVf + off) = hi;
                            *(u32x4*)(KVf + off + 6144) = lo;
                        }
                    }
            } else {
                u16* vp = KVf + (size_t)(bh * 64 + (nw0 >> 5)) * 18432 + 12288 + lane * 8;
                #pragma unroll
                for (int d = 0; d < 12; ++d) {
                    unsigned int t[8];
                    #pragma unroll
                    for (int e = 0; e < 8; ++e)
                        t[e] = L[gq * 8 + e][d * 16 + lq];
                    u32x4 pk = { (t[0] & 0xffffu) | (t[1] << 16), (t[2] & 0xffffu) | (t[3] << 16),
                                 (t[4] & 0xffffu) | (t[5] << 16), (t[6] & 0xffffu) | (t[7] << 16) };
                    *(u32x4*)(vp + d * 512) = pk;
                }
            }
        }
    }
}

// ---------------- K2: MFMA flash attention (R11 loop), 32 i-rows/wave --------
// grid 512 (XCD-swizzled), block 256, launch_bounds(256,2) -> 2 waves/SIMD,
// 72KB dbuf -> 2 blocks/CU. Epilogue: LDS transpose -> COALESCED u32x4 stores of
// the unnormalized bf16 half-plane in att2-scatter layout + per-row (m,l).
__global__ __launch_bounds__(256, 2) void attn_mfma(
    const u16* __restrict__ Qhi, const u16* __restrict__ Qlo,
    const u16* __restrict__ KVf, u16* __restrict__ OpA, u16* __restrict__ OpB,
    float2* __restrict__ MLp) {
    __shared__ __align__(16) u16 lds[2][18432];  // per buf: Khi[6144]|Klo[6144]|V[6144]
    const int tid = threadIdx.x;
    const int lane = tid & 63;
    const int wl = tid >> 6;         // 0..3
    const int g = lane >> 4;         // 0..3
    const int i = lane & 15;
    const int id = blockIdx.x;                     // 0..511
    const int rem = id >> 3;                       // 0..63
    const int grp = ((rem >> 4) << 3) | (id & 7);  // 0..31: (bh,half)
    const int itile = rem & 15;                    // 0..15
    const int bh = grp >> 1;
    const int half = grp & 1;

    // Q B-frags resident (hi+lo) for both 16-row sets: 96 VGPRs
    bf16x8 qh[2][6], ql[2][6];
    #pragma unroll
    for (int is = 0; is < 2; ++is) {
        size_t qb = (size_t)(bh * 128 + itile * 8 + wl * 2 + is) * 3072 + (size_t)lane * 8;
        #pragma unroll
        for (int kc = 0; kc < 6; ++kc) {
            qh[is][kc] = *(const bf16x8*)(Qhi + qb + kc * 512);
            ql[is][kc] = *(const bf16x8*)(Qlo + qb + kc * 512);
        }
    }

    const char* gKV = (const char*)KVf + (size_t)bh * 2359296;  // 64 tiles * 36864 B
    auto stage = [&](int buf, int jtAbs) {
        const char* src = gKV + (size_t)jtAbs * 36864;
        char* dst = (char*)&lds[buf][0];
        #pragma unroll
        for (int s = 0; s < 9; ++s) {
            const int c16 = (tid + s * 256) * 16;
            gload16(src + c16, dst + c16);
        }
    };

    const int jt0 = half * 32;
    stage(0, jt0);
    __syncthreads();
    int cur = 0;

    f32x4v o[2][12] = {};
    float m_run[2] = {-1e30f, -1e30f}, l_run[2] = {0.f, 0.f};

    for (int t = 0; t < 32; ++t) {
        if (t + 1 < 32) stage(cur ^ 1, jt0 + t + 1);
        const u16* L = &lds[cur][0];

        // ---- S^T = K · Q^T : K frags read once, 4 indep chains x 3 seq terms ----
        f32x4v s4[2][2] = {};   // [iset][js]
        __builtin_amdgcn_s_setprio(1);
        #pragma unroll
        for (int kc = 0; kc < 6; ++kc) {
            bf16x8 kh0 = *(const bf16x8*)&L[(unsigned)(kc * 512) + lane * 8];
            bf16x8 kh1 = *(const bf16x8*)&L[(unsigned)((6 + kc) * 512) + lane * 8];
            bf16x8 kl0 = *(const bf16x8*)&L[6144u + (unsigned)(kc * 512) + lane * 8];
            bf16x8 kl1 = *(const bf16x8*)&L[6144u + (unsigned)((6 + kc) * 512) + lane * 8];
            s4[0][0] = MFMA16(kh0, qh[0][kc], s4[0][0]);
            s4[0][1] = MFMA16(kh1, qh[0][kc], s4[0][1]);
            s4[1][0] = MFMA16(kh0, qh[1][kc], s4[1][0]);
            s4[1][1] = MFMA16(kh1, qh[1][kc], s4[1][1]);
            s4[0][0] = MFMA16(kh0, ql[0][kc], s4[0][0]);
            s4[0][1] = MFMA16(kh1, ql[0][kc], s4[0][1]);
            s4[1][0] = MFMA16(kh0, ql[1][kc], s4[1][0]);
            s4[1][1] = MFMA16(kh1, ql[1][kc], s4[1][1]);
            s4[0][0] = MFMA16(kl0, qh[0][kc], s4[0][0]);
            s4[0][1] = MFMA16(kl1, qh[0][kc], s4[0][1]);
            s4[1][0] = MFMA16(kl0, qh[1][kc], s4[1][0]);
            s4[1][1] = MFMA16(kl1, qh[1][kc], s4[1][1]);
        }
        __builtin_amdgcn_s_setprio(0);

        // ---- online softmax (log2 domain) per i-set + P B-frag build ----
        bf16x8 pb[2];
        #pragma unroll
        for (int is = 0; is < 2; ++is) {
            float pm = -1e30f;
            #pragma unroll
            for (int js = 0; js < 2; ++js)
                #pragma unroll
                for (int r = 0; r < 4; ++r) pm = fmaxf(pm, s4[is][js][r]);
            pm = fmaxf(pm, __shfl_xor(pm, 16, 64));
            pm = fmaxf(pm, __shfl_xor(pm, 32, 64));
            if (!__all(pm <= m_run[is] + 8.0f)) {   // T13 defer-rescale
                float mnew = fmaxf(m_run[is], pm);
                float sc = exp2f(m_run[is] - mnew);
                l_run[is] *= sc;
                #pragma unroll
                for (int d = 0; d < 12; ++d) o[is][d] = o[is][d] * sc;
                m_run[is] = mnew;
            }
            float rs = 0.f;
            unsigned int w0[2], w1[2];
            #pragma unroll
            for (int js = 0; js < 2; ++js) {
                float p0 = exp2f(s4[is][js][0] - m_run[is]), p1 = exp2f(s4[is][js][1] - m_run[is]);
                float p2 = exp2f(s4[is][js][2] - m_run[is]), p3 = exp2f(s4[is][js][3] - m_run[is]);
                rs += (p0 + p1) + (p2 + p3);
                w0[js] = pack2(p0, p1);
                w1[js] = pack2(p2, p3);
            }
            rs += __shfl_xor(rs, 16, 64);
            rs += __shfl_xor(rs, 32, 64);
            l_run[is] += rs;

            // P^T B-frag: F[t] holds k=j'=g*8+2t,2t+1, col=i
            u32x4 F;
            const int slA = ((g & 1) << 5) + i;
            const int slB = slA + 16;
            const bool ghi = (g >> 1) != 0;
            { unsigned a0 = __shfl((int)w0[0], slA, 64), a1 = __shfl((int)w0[1], slA, 64); F[0] = ghi ? a1 : a0; }
            { unsigned a0 = __shfl((int)w1[0], slA, 64), a1 = __shfl((int)w1[1], slA, 64); F[1] = ghi ? a1 : a0; }
            { unsigned a0 = __shfl((int)w0[0], slB, 64), a1 = __shfl((int)w0[1], slB, 64); F[2] = ghi ? a1 : a0; }
            { unsigned a0 = __shfl((int)w1[0], slB, 64), a1 = __shfl((int)w1[1], slB, 64); F[3] = ghi ? a1 : a0; }
            pb[is] = __builtin_bit_cast(bf16x8, F);
        }

        // ---- O^T += V^T · P^T : V frags read once, used by both i-sets ----
        __builtin_amdgcn_s_setprio(1);
        #pragma unroll
        for (int d = 0; d < 12; ++d) {
            bf16x8 vf = *(const bf16x8*)&L[12288u + (unsigned)(d * 512) + lane * 8];
            o[0][d] = MFMA16(vf, pb[0], o[0][d]);
            o[1][d] = MFMA16(vf, pb[1], o[1][d]);
        }
        __builtin_amdgcn_s_setprio(0);

        if (t + 1 < 32) {
            __syncthreads();   // drains vmcnt: next buffer staged; cur reads done
            cur ^= 1;
        }
    }

    // ---- epilogue: LDS transpose (row-stride 196 u16, 2-way banks) ----
    __syncthreads();   // all waves done reading lds
    u16* LS = &lds[0][0];
    #pragma unroll
    for (int is = 0; is < 2; ++is) {
        const int row = (wl * 2 + is) * 16 + i;
        #pragma unroll
        for (int d = 0; d < 12; ++d) {
            u32x2 pk = { pack2(o[is][d][0], o[is][d][1]), pack2(o[is][d][2], o[is][d][3]) };
            *(u32x2*)&LS[row * 196 + d * 16 + g * 4] = pk;
        }
        if (g == 0) {
            const int ig = itile * 128 + row;
            float2 ml; ml.x = m_run[is]; ml.y = l_run[is];
            MLp[(size_t)half * 32768 + bh * 2048 + ig] = ml;
        }
    }
    __syncthreads();
    // coalesced store: 12 x u32x4 per thread, exactly covering the 128x192 plane
    const int b2 = bh >> 3, hh = bh & 7;
    u16* P = half ? OpB : OpA;
    #pragma unroll
    for (int v = 0; v < 12; ++v) {
        const int Lx = v * 256 + tid;        // 0..3071
        const int ln   = Lx & 63;
        const int itql = (Lx >> 6) & 3;
        const int ksl  = (Lx >> 8) & 3;
        const int c    = Lx >> 10;           // 0..2
        const int i31 = ln & 31, b5 = ln >> 5;
        const int rowl = itql * 32 + i31;
        unsigned tv[8];
        #pragma unroll
        for (int e = 0; e < 8; ++e) {
            const int dd = ksl * 16 + b5 * 8 + e;
            tv[e] = LS[rowl * 196 + dd * 3 + c];
        }
        u32x4 pk = { tv[0] | (tv[1] << 16), tv[2] | (tv[3] << 16),
                     tv[4] | (tv[5] << 16), tv[6] | (tv[7] << 16) };
        size_t off = (((size_t)(b2 * 3 + c) * 32 + (hh * 4 + ksl)) * 64 + (itile * 4 + itql)) * 512
                     + (size_t)ln * 8;
        *(u32x4*)(P + off) = pk;
    }
}

// ---------------- K3: output projection + inline flash merge -----------------
__global__ __launch_bounds__(256) void out_mfma(const u16* __restrict__ OpA,
                                                const u16* __restrict__ OpB,
                                                const float2* __restrict__ MLp,
                                                const float* __restrict__ wo,
                                                float* __restrict__ out) {
    const int tid = threadIdx.x, lane = tid & 63, w = tid >> 6, hf = lane >> 5, l31 = lane & 31;
    const int o0 = blockIdx.x * 32;
    const int n5 = blockIdx.y * 4 + w;
    const int b = blockIdx.z;
    const float* wp = wo + (size_t)(o0 + l31) * 512 + hf * 8;

    // per-hh merge weights for this lane's row n = n5*32 + l31
    float wa[8], wb[8], inv[8];
    #pragma unroll
    for (int hh = 0; hh < 8; ++hh) {
        size_t mi = (size_t)(b * 8 + hh) * 2048 + n5 * 32 + l31;
        float2 A = MLp[mi];
        float2 Bm = MLp[32768 + mi];
        float mm = fmaxf(A.x, Bm.x);
        wa[hh] = exp2f(A.x - mm);
        wb[hh] = exp2f(Bm.x - mm);
        inv[hh] = 1.0f / (A.y * wa[hh] + Bm.y * wb[hh]);
    }

    f32x16 acc[3] = {};
    #pragma unroll 2
    for (int ks = 0; ks < 32; ++ks) {
        const int hh = ks >> 2;
        const float waH = wa[hh], wbH = wb[hh], invH = inv[hh];
        bf16x8 wh, wl;
        {
            f32x4v t0 = *(const f32x4v*)(wp + ks * 16);
            f32x4v t1 = *(const f32x4v*)(wp + ks * 16 + 4);
            #pragma unroll
            for (int e = 0; e < 4; ++e) {
                { float v = t0[e]; __bf16 hi = (__bf16)v; wh[e] = hi; wl[e] = (__bf16)(v - (float)hi); }
                { float v = t1[e]; __bf16 hi = (__bf16)v; wh[4 + e] = hi; wl[4 + e] = (__bf16)(v - (float)hi); }
            }
        }
        #pragma unroll
        for (int c = 0; c < 3; ++c) {
            size_t pc = (size_t)(b * 3 + c) * 1048576 + (size_t)ks * 32768 + (size_t)n5 * 512 + (size_t)lane * 8;
            u32x4 aA = *(const u32x4*)(OpA + pc);
            u32x4 aB = *(const u32x4*)(OpB + pc);
            unsigned hiw[4], low[4];
            #pragma unroll
            for (int q = 0; q < 4; ++q) {
                unsigned ha = 0, la = 0;
                #pragma unroll
                for (int s = 0; s < 2; ++s) {
                    u16 ua = (u16)((aA[q] >> (s * 16)) & 0xffffu);
                    u16 ub = (u16)((aB[q] >> (s * 16)) & 0xffffu);
                    float v = (fb16(ua) * waH + fb16(ub) * wbH) * invH;
                    u16 hv = b16(v);
                    u16 lv = b16(v - fb16(hv));
                    ha |= ((unsigned)hv) << (s * 16);
                    la |= ((unsigned)lv) << (s * 16);
                }
                hiw[q] = ha; low[q] = la;
            }
            union { bf16x8 v; u32x4 u; } H, Lo;
            H.u  = { hiw[0], hiw[1], hiw[2], hiw[3] };
            Lo.u = { low[0], low[1], low[2], low[3] };
            acc[c] = MFMA(H.v, wh, acc[c]);
            acc[c] = MFMA(Lo.v, wh, acc[c]);
            acc[c] = MFMA(H.v, wl, acc[c]);
        }
    }
    #pragma unroll
    for (int r = 0; r < 16; ++r) {
        int n = (n5 << 5) + (r & 3) + 8 * (r >> 2) + 4 * hf;
        size_t off = ((size_t)(b * 2048 + n) * 256 + o0 + l31) * 3;
        out[off]     = acc[0][r];
        out[off + 1] = acc[1][r];
        out[off + 2] = acc[2][r];
    }
}

extern "C" void kernel_launch(void* const* d_in, const int* in_sizes, int n_in,
                              void* d_out, int out_size, void* d_ws, size_t ws_size,
                              hipStream_t stream) {
    const float* x     = (const float*)d_in[0];
    const float* w_qkv = (const float*)d_in[1];
    const float* w_out = (const float*)d_in[2];
    float* out = (float*)d_out;

    const size_t NB = (size_t)16 * 2048 * 192;       // 6.29M u16 per plane
    const size_t KVN = (size_t)16 * 64 * 18432;      // 18.87M u16 (37.7MB)
    u16* Qhi = (u16*)d_ws;
    u16* Qlo = Qhi + NB;
    u16* KVf = Qlo + NB;
    u16* OpA = KVf + KVN;                            // 12.6MB
    u16* OpB = OpA + NB;                             // 12.6MB
    float2* MLp = (float2*)(OpB + NB);               // 2*32768 float2 = 512KB

    qkv_mfma<<<dim3(768), 256, 0, stream>>>(x, w_qkv, Qhi, Qlo, KVf);
    attn_mfma<<<dim3(512), 256, 0, stream>>>(Qhi, Qlo, KVf, OpA, OpB, MLp);
    out_mfma<<<dim3(8, 16, 2), 256, 0, stream>>>(OpA, OpB, MLp, w_out, out);
}